// Round 10
// baseline (266.351 us; speedup 1.0000x reference)
//
#include <hip/hip_runtime.h>

#define NSP   25600   // 25*32*32 spatial elems per (b, channel)
#define HWC   1024    // 32*32

typedef __attribute__((ext_vector_type(8))) short bf8;   // 8 bf16 = 4 VGPRs
typedef __attribute__((ext_vector_type(4))) float f4;    // MFMA C/D frag
#define MFMA(a,b,c) __builtin_amdgcn_mfma_f32_16x16x32_bf16(a, b, c, 0, 0, 0)
typedef unsigned short u16;

__device__ __forceinline__ u16 f2b(float f) {
    union { float f; unsigned u; } v; v.f = f;
    unsigned r = v.u + 0x7fffu + ((v.u >> 16) & 1u);
    return (u16)(r >> 16);
}
__device__ __forceinline__ float b2f(u16 h) {
    union { unsigned u; float f; } v; v.u = ((unsigned)h) << 16;
    return v.f;
}

// Attention addressing (K re-chunked into 32-contig-elem blocks; legal since
// fold K-order only needs consistency between q/k/v/unfold).
__device__ __forceinline__ long row_base(int att, int b, int m) {
    if (att == 0) { int cc = m >> 5, h = m & 31;   return ((long)(b*128 + cc))*NSP + h*32; }
    else if (att == 1) { int cc = m / 5, u = m - cc*5; return ((long)(b*128 + 32 + cc))*NSP + u*5120; }
    else { int h = m / 5, u = m - h*5;            return ((long)(b*128 + 64))*NSP + u*5120 + h*32; }
}
__device__ __forceinline__ long chunk_off(int att, int kc) {
    if (att == 0) return (long)kc * 1024;
    else if (att == 1) return (long)kc * 32;
    else { int cc = kc / 5, v = kc - cc*5; return (long)cc*NSP + v*1024; }
}

// ---------------- K0: one-time weight convert (+ fused W2@Wo) --------------
__global__ __launch_bounds__(256) void k_prep(
        const float* __restrict__ Wi, const float* __restrict__ Wk,
        const float* __restrict__ W1, const float* __restrict__ W2,
        const float* __restrict__ Wo, u16* __restrict__ wbt,
        u16* __restrict__ w2o) {
    int x = blockIdx.x, tid = threadIdx.x;
    if (x < 224) {
        int e = x * 256 + tid;                   // 57344 total
        const float* src; int base, K, N;
        if (e < 8192)       { src = Wi; base = 0;     K = 64;  N = 128; }
        else if (e < 16384) { src = Wk; base = 8192;  K = 64;  N = 128; }
        else if (e < 32768) { src = W1; base = 16384; K = 128; N = 128; }
        else if (e < 49152) { src = W2; base = 32768; K = 128; N = 128; }
        else                { src = Wo; base = 49152; K = 128; N = 64;  }
        int local = e - base, n = local / K, k = local - n * K;
        wbt[e] = f2b(src[k * N + n]);
    } else {
        int e = (x - 224) * 256 + tid;           // 8192 = 64 o x 128 k
        int o = e >> 7, k = e & 127;
        float s = 0.f;
        for (int n = 0; n < 128; ++n) s += W2[k * 128 + n] * Wo[n * 64 + o];
        w2o[e] = f2b(s);
    }
}

// ---------------- K1: token GEMMs (MFMA) -> bf16 q / kv --------------------
__global__ __launch_bounds__(256) void k_tokens(
        const float* __restrict__ x_hf, const float* __restrict__ x_lf,
        const u16* __restrict__ wbt,
        u16* __restrict__ qb, u16* __restrict__ kvb) {
    // grid (400, 4, 2)
    int s0 = blockIdx.x * 64, b = blockIdx.y, which = blockIdx.z;
    const float* x  = which ? x_lf : x_hf;
    const u16* Wb = wbt + (which ? 8192 : 0);    // [d][c] bf16
    u16* out = which ? kvb : qb;
    __shared__ u16 Axs[64 * 72];   // [token][c]
    __shared__ u16 Wl [128 * 72];  // [d][c]
    int tid = threadIdx.x;
    for (int g = tid; g < 1024; g += 256) {      // W stage: 16B contiguous
        int d = g >> 3, c8 = (g & 7) * 8;
        *(bf8*)&Wl[d * 72 + c8] = *(const bf8*)(Wb + d * 64 + c8);
    }
    for (int g = tid; g < 1024; g += 256) {      // x transpose, packed x4
        int s = g & 63, c4 = (g >> 6) * 4;
        long xb = ((long)(b * 64 + c4)) * NSP + s0 + s;
        ushort4 pk;
        pk.x = f2b(x[xb]);
        pk.y = f2b(x[xb + NSP]);
        pk.z = f2b(x[xb + 2 * NSP]);
        pk.w = f2b(x[xb + 3 * NSP]);
        *(ushort4*)&Axs[s * 72 + c4] = pk;
    }
    __syncthreads();
    int w = tid >> 6, l = tid & 63, quad = l >> 4, col = l & 15;
    f4 z = {0.f, 0.f, 0.f, 0.f};
    f4 acc[8]; for (int i = 0; i < 8; ++i) acc[i] = z;
#pragma unroll
    for (int kc = 0; kc < 2; ++kc) {
        bf8 a = *(bf8*)&Axs[(w * 16 + col) * 72 + kc * 32 + quad * 8];
#pragma unroll
        for (int nt = 0; nt < 8; ++nt) {
            bf8 bb = *(bf8*)&Wl[(nt * 16 + col) * 72 + kc * 32 + quad * 8];
            acc[nt] = MFMA(a, bb, acc[nt]);
        }
    }
#pragma unroll
    for (int nt = 0; nt < 8; ++nt) {
        int d = nt * 16 + col;
        long base = ((long)(b * 128 + d)) * NSP + s0 + w * 16 + quad * 4;
        ushort4 pk;
        pk.x = f2b(acc[nt][0]); pk.y = f2b(acc[nt][1]);
        pk.z = f2b(acc[nt][2]); pk.w = f2b(acc[nt][3]);
        *(ushort4*)(out + base) = pk;
    }
}

// ---------------- K3: MERGED S-GEMMs + V^T transposes + norms --------------
// att0 sgemm: 64x64 tiles, BK=64 (R8 proven: 8 MFMA per barrier-pair, 136
// tiles keep parallelism). vt att1/2 batched 5x (block = 160p x 32f).
// Ranges: [0,136) att0; [136,586) split-K; [586,786) vt att0;
//         [786,946) vt att1; [946,1266) vt att2; [1266,1938) norms.
__global__ __launch_bounds__(256) void k_sgemm_all(
        const u16* __restrict__ qb, const u16* __restrict__ kvb,
        u16* __restrict__ vt0, u16* __restrict__ vt1, u16* __restrict__ vt2,
        float* __restrict__ nq, float* __restrict__ nk,
        u16* __restrict__ Sb, float* __restrict__ Spart) {
    __shared__ __align__(16) u16 lds[2 * 64 * 72];   // 18,432 B
    int x = blockIdx.x, b = blockIdx.y;
    int tid = threadIdx.x, w = tid >> 6, l = tid & 63, quad = l >> 4, col = l & 15;
    if (x < 136) {
        u16* Qs = lds;                // 64 x 72 (two 32-chunks per row)
        u16* Ks = lds + 64 * 72;
        int t = x, i = 0;
        while (t >= (i + 1) * (i + 2) / 2) ++i;
        int j = t - i * (i + 1) / 2;
        int mt = i * 64, nt = j * 64;
        int srow = tid >> 2, g = tid & 3;
        int mr = mt + srow, nr = nt + srow;
        long qrow = ((long)(b * 128 + (mr >> 5))) * NSP + (mr & 31) * 32;
        long krow = ((long)(b * 128 + (nr >> 5))) * NSP + (nr & 31) * 32;
        f4 z = {0.f, 0.f, 0.f, 0.f};
        f4 acc[4]; for (int q = 0; q < 4; ++q) acc[q] = z;
        for (int kc = 0; kc < 25; kc += 2) {     // BK=64 (2 chunks/stage)
            long co = (long)kc * 1024;
            bool two = (kc + 1 < 25);
            *(bf8*)&Qs[srow * 72 + g * 8] = *(const bf8*)(qb + qrow + co + g * 8);
            *(bf8*)&Ks[srow * 72 + g * 8] = *(const bf8*)(kvb + krow + co + g * 8);
            if (two) {
                *(bf8*)&Qs[srow * 72 + 32 + g * 8] =
                    *(const bf8*)(qb + qrow + co + 1024 + g * 8);
                *(bf8*)&Ks[srow * 72 + 32 + g * 8] =
                    *(const bf8*)(kvb + krow + co + 1024 + g * 8);
            }
            __syncthreads();
            bf8 a0 = *(bf8*)&Qs[(w * 16 + col) * 72 + quad * 8];
#pragma unroll
            for (int t2 = 0; t2 < 4; ++t2) {
                bf8 bb = *(bf8*)&Ks[(t2 * 16 + col) * 72 + quad * 8];
                acc[t2] = MFMA(a0, bb, acc[t2]);
            }
            if (two) {
                bf8 a1 = *(bf8*)&Qs[(w * 16 + col) * 72 + 32 + quad * 8];
#pragma unroll
                for (int t2 = 0; t2 < 4; ++t2) {
                    bf8 bb = *(bf8*)&Ks[(t2 * 16 + col) * 72 + 32 + quad * 8];
                    acc[t2] = MFMA(a1, bb, acc[t2]);
                }
            }
            __syncthreads();
        }
#pragma unroll
        for (int t2 = 0; t2 < 4; ++t2)
#pragma unroll
            for (int r = 0; r < 4; ++r) {
                int m = mt + w * 16 + quad * 4 + r, n = nt + t2 * 16 + col;
                float v = (n <= m) ? acc[t2][r] : 0.f;      // RAW (norm deferred)
                Sb[((long)b * 1024 + m) * 1024 + n] = f2b(v);
            }
    } else if (x < 586) {
        float* fl = (float*)lds;                 // 4096 floats = 16 KB
        int x2 = x - 136;                        // 0..449
        int t = x2 % 15, y = x2 / 15;            // y 0..29
        int att, split, nsplit; float* base;
        if (y < 10) { att = 1; split = y;      nsplit = 10; base = Spart; }
        else        { att = 2; split = y - 10; nsplit = 20; base = Spart + 614400; }
        int i = 0;
        while (t >= (i + 1) * (i + 2) / 2) ++i;
        int j = t - i * (i + 1) / 2;
        int mt = i * 32, nt = j * 32;
        long rm0 = row_base(att, b, mt + col),      rm1 = row_base(att, b, mt + 16 + col);
        long rn0 = row_base(att, b, nt + col),      rn1 = row_base(att, b, nt + 16 + col);
        int ko = quad * 8;
        f4 z = {0.f, 0.f, 0.f, 0.f};
        f4 a00 = z, a01 = z, a10 = z, a11 = z;
#pragma unroll
        for (int s = 0; s < 4; ++s) {
            int kc = split * 16 + w * 4 + s;
            long co = chunk_off(att, kc);
            bf8 qa0 = *(const bf8*)(qb + rm0 + co + ko);
            bf8 qa1 = *(const bf8*)(qb + rm1 + co + ko);
            bf8 kb0 = *(const bf8*)(kvb + rn0 + co + ko);
            bf8 kb1 = *(const bf8*)(kvb + rn1 + co + ko);
            a00 = MFMA(qa0, kb0, a00); a01 = MFMA(qa0, kb1, a01);
            a10 = MFMA(qa1, kb0, a10); a11 = MFMA(qa1, kb1, a11);
        }
        float* my = fl + w * 1024;
#pragma unroll
        for (int r = 0; r < 4; ++r) {
            my[(quad * 4 + r) * 32 + col]            = a00[r];
            my[(quad * 4 + r) * 32 + 16 + col]       = a01[r];
            my[(16 + quad * 4 + r) * 32 + col]       = a10[r];
            my[(16 + quad * 4 + r) * 32 + 16 + col]  = a11[r];
        }
        __syncthreads();
        float* dst = base + ((long)((b * 15 + t) * nsplit + split)) * 1024;
        for (int e = tid; e < 1024; e += 256)
            dst[e] = fl[e] + fl[1024 + e] + fl[2048 + e] + fl[3072 + e];
    } else if (x < 786) {                        // vt att0: 128 p x 32 f
        u16* T = lds;                            // 128 x 36
        int xv = x - 586;                        // 0..199
        int kc = xv >> 3, pt = (xv & 7) * 128;
        long co = (long)kc * 1024;
#pragma unroll
        for (int i = 0; i < 4; ++i) {
            int idx = i * 256 + tid;
            int r = idx >> 3, fq = (idx & 7) * 4;
            ushort4 e = *(const ushort4*)(kvb + row_base(0, b, pt + r) + co + fq);
            *(ushort4*)&T[r * 36 + fq] = e;
        }
        __syncthreads();
#pragma unroll
        for (int i = 0; i < 4; ++i) {
            int idx = i * 256 + tid;
            int f = idx >> 5, p4 = (idx & 31) * 4;
            ushort4 pk;
            pk.x = T[(p4    ) * 36 + f];
            pk.y = T[(p4 + 1) * 36 + f];
            pk.z = T[(p4 + 2) * 36 + f];
            pk.w = T[(p4 + 3) * 36 + f];
            *(ushort4*)(vt0 + (((long)b * 25 + kc) * 32 + f) * 1024 + pt + p4) = pk;
        }
    } else if (x < 1266) {                       // vt att1/2 BATCHED: 160p x 32f
        u16* T = lds;                            // 160 x 36 = 11.5 KB
        int att, kc, KC; u16* vt;
        if (x < 946) { att = 1; kc = x - 786; KC = 160; vt = vt1; }
        else         { att = 2; kc = x - 946; KC = 320; vt = vt2; }
        long co = chunk_off(att, kc);
        for (int g = tid; g < 1280; g += 256) {  // read 160 rows x 32 f
            int r = g >> 3, fq = (g & 7) * 4;
            ushort4 e = *(const ushort4*)(kvb + row_base(att, b, r) + co + fq);
            *(ushort4*)&T[r * 36 + fq] = e;
        }
        __syncthreads();
        for (int g = tid; g < 1280; g += 256) {  // write 32 f x 160 p
            int f = g / 40, p4 = (g % 40) * 4;
            ushort4 pk;
            pk.x = T[(p4    ) * 36 + f];
            pk.y = T[(p4 + 1) * 36 + f];
            pk.z = T[(p4 + 2) * 36 + f];
            pk.w = T[(p4 + 3) * 36 + f];
            *(ushort4*)(vt + (((long)b * KC + kc) * 32 + f) * 160 + p4) = pk;
        }
    } else {                                     // norms -> store RECIPROCAL
        int x2 = x - 1266;                       // 0..671
        int which = x2 >= 336;
        int g = which ? x2 - 336 : x2;           // 0..335
        int att, m0, KC;
        if (g < 256)      { att = 0; m0 = g * 4;         KC = 25;  }
        else if (g < 296) { att = 1; m0 = (g - 256) * 4; KC = 160; }
        else              { att = 2; m0 = (g - 296) * 4; KC = 320; }
        const u16* src = which ? kvb : qb;
        float* dst = which ? nk : nq;
        int ww = tid >> 6, lane = tid & 63;
        int m = m0 + ww;
        long base = row_base(att, b, m);
        int K = KC * 32;
        float s = 0.f;
        for (int k8 = lane * 8; k8 < K; k8 += 512) {
            bf8 v = *(const bf8*)(src + base + chunk_off(att, k8 >> 5) + (k8 & 31));
#pragma unroll
            for (int j = 0; j < 8; ++j) { float f = b2f(((u16*)&v)[j]); s += f * f; }
        }
        for (int o = 32; o >= 1; o >>= 1) s += __shfl_xor(s, o);
        if (lane == 0) {
            int off = (att == 0) ? b * 1024 + m
                                 : ((att == 1) ? 4096 : 4736) + b * 160 + m;
            dst[off] = 1.f / fmaxf(sqrtf(s), 1e-12f);
        }
    }
}

// ---------------- K4: fused softmaxes (applies normalization) --------------
__global__ __launch_bounds__(256) void k_softmax_all(
        const u16* __restrict__ Sb, u16* __restrict__ Pb,
        const float* __restrict__ Spart, const float* __restrict__ nq,
        const float* __restrict__ nk, u16* __restrict__ Pb12) {
    // grid (576, 4): x<256 -> att0 wave-per-row; else att1/2 column softmax
    int xb = blockIdx.x, b = blockIdx.y, tid = threadIdx.x;
    if (xb < 256) {
        int w = tid >> 6, lane = tid & 63;
        int m = xb * 4 + w;
        const u16* row = Sb + ((long)b * 1024 + m) * 1024;
        u16* pr = Pb + ((long)b * 1024 + m) * 1024;
        int e0 = lane * 16;
        float rq = nq[b * 1024 + m];             // reciprocal norms
        const float* nkb = nk + b * 1024 + e0;
        float rk[16];
        *(float4*)&rk[0]  = *(const float4*)(nkb);
        *(float4*)&rk[4]  = *(const float4*)(nkb + 4);
        *(float4*)&rk[8]  = *(const float4*)(nkb + 8);
        *(float4*)&rk[12] = *(const float4*)(nkb + 12);
        bf8 x0 = *(const bf8*)(row + e0);
        bf8 x1 = *(const bf8*)(row + e0 + 8);
        float v[16];
#pragma unroll
        for (int j = 0; j < 8; ++j) {
            v[j]     = b2f(((u16*)&x0)[j]) * rq * rk[j];
            v[8 + j] = b2f(((u16*)&x1)[j]) * rq * rk[8 + j];
        }
        float mx = -1e30f;
#pragma unroll
        for (int j = 0; j < 16; ++j) if (e0 + j <= m) mx = fmaxf(mx, v[j]);
#pragma unroll
        for (int o = 32; o >= 1; o >>= 1) mx = fmaxf(mx, __shfl_xor(mx, o));
        float s = 0.f;
#pragma unroll
        for (int j = 0; j < 16; ++j) {
            float e = (e0 + j <= m) ? __expf(v[j] - mx) : 0.f;
            v[j] = e; s += e;
        }
#pragma unroll
        for (int o = 32; o >= 1; o >>= 1) s += __shfl_xor(s, o);
        float inv = 1.f / s;
        bf8 o0, o1;
#pragma unroll
        for (int j = 0; j < 8; ++j) {
            ((u16*)&o0)[j] = f2b(v[j] * inv);
            ((u16*)&o1)[j] = f2b(v[8 + j] * inv);
        }
        *(bf8*)(pr + e0) = o0;
        *(bf8*)(pr + e0 + 8) = o1;
    } else {
        int x = xb - 256;                        // 0..319
        int att = (x < 160) ? 1 : 2;
        int m = (att == 1) ? x : x - 160;
        int nsplit = (att == 1) ? 10 : 20;
        const float* base = (att == 1) ? Spart : Spart + 614400;
        int noff = (att == 1) ? 4096 : 4736;
        u16* P = Pb12 + ((att == 1) ? 0 : 102400);
        int i = m >> 5, ro = (m & 31) * 32;
        int n = tid;
        bool act = (n <= m) && (n < 160);
        float myv = 0.f;
        if (act) {
            int t = i * (i + 1) / 2 + (n >> 5);
            const float* src = base + ((long)((b * 15 + t) * nsplit)) * 1024 + ro + (n & 31);
            float s = 0.f;
            for (int sp = 0; sp < nsplit; ++sp) s += src[(long)sp * 1024];
            myv = s * (nq[noff + b * 160 + m] * nk[noff + b * 160 + n]);  // reciprocals
        }
        __shared__ float red[256];
        red[tid] = act ? myv : -1e30f; __syncthreads();
        for (int w = 128; w >= 1; w >>= 1) {
            if (tid < w) red[tid] = fmaxf(red[tid], red[tid + w]);
            __syncthreads();
        }
        float mx = red[0]; __syncthreads();
        float e = act ? __expf(myv - mx) : 0.f;
        red[tid] = e; __syncthreads();
        for (int w = 128; w >= 1; w >>= 1) {
            if (tid < w) red[tid] += red[tid + w];
            __syncthreads();
        }
        float inv = 1.f / red[0];
        if (n < 160) P[((long)b * 160 + m) * 160 + n] = f2b(e * inv);
    }
}

// ---------------- K5: fused O-GEMMs + residual (att0 widened to 64f) -------
// att0: block = 64m x 64f (2 kc chunks), 208 blocks/batch (16 mtt x 13 fg).
//       Per 64-p slab: P staged ONCE for both kc (4x256 loads), 8 MFMA per
//       barrier-pair (was 4). Attempted P traffic halves vs 32f blocks.
// att1/2: R3 proven: V[16f][160p] staged once; direct-L2 P reads.
__global__ __launch_bounds__(256) void k_ogemm_all(
        const u16* __restrict__ Pb, const u16* __restrict__ vt0,
        const u16* __restrict__ Pb12, const u16* __restrict__ vt1,
        const u16* __restrict__ vt2, const u16* __restrict__ kvb,
        u16* __restrict__ catb) {
    // grid (1168, 4): x<208 -> att0; 208..527 -> att1; 528..1167 -> att2
    __shared__ __align__(16) u16 lds[64 * 72 + 64 * 72];   // 18,432 B
    int x = blockIdx.x, b = blockIdx.y;
    int tid = threadIdx.x, w = tid >> 6, l = tid & 63, quad = l >> 4, col = l & 15;
    if (x < 208) {
        int fg = x % 13, mtt = 15 - x / 13;      // heavy (mtt=15) first
        int mt = mtt * 64;
        int nf = (fg == 12) ? 2 : 4;             // f-tiles (fg=12: only kc 24)
        u16* Ps = lds;              // 64 x 72 (m rows, p-slab 64)
        u16* Vs = lds + 64 * 72;    // 64 x 72 (f rows, p-slab 64)
        f4 z = {0.f, 0.f, 0.f, 0.f};
        f4 acc[4];
#pragma unroll
        for (int i = 0; i < 4; ++i) acc[i] = z;
        for (int s = 0; s <= mtt; ++s) {         // p = 0 .. mt+64
            int p0 = s * 64;
#pragma unroll
            for (int i = 0; i < 2; ++i) {        // P stage: 64 x 64
                int idx = i * 256 + tid;
                int row = idx >> 3, c8 = (idx & 7) * 8;
                *(bf8*)&Ps[row * 72 + c8] =
                    *(const bf8*)(Pb + ((long)(b * 1024 + mt + row)) * 1024 + p0 + c8);
            }
#pragma unroll
            for (int i = 0; i < 2; ++i) {        // V stage: (nf*16) f x 64 p
                int idx = i * 256 + tid;
                int f = idx >> 3, p8 = (idx & 7) * 8;
                if (f < nf * 16) {
                    int kc = fg * 2 + (f >> 5), fr = f & 31;
                    *(bf8*)&Vs[f * 72 + p8] =
                        *(const bf8*)(vt0 + (((long)(b * 25 + kc)) * 32 + fr) * 1024 + p0 + p8);
                }
            }
            __syncthreads();
            bf8 a0 = *(bf8*)&Ps[(w * 16 + col) * 72 + quad * 8];
            bf8 a1 = *(bf8*)&Ps[(w * 16 + col) * 72 + 32 + quad * 8];
#pragma unroll
            for (int t2 = 0; t2 < 4; ++t2) {
                if (t2 >= nf) break;
                bf8 b0 = *(bf8*)&Vs[(t2 * 16 + col) * 72 + quad * 8];
                bf8 b1 = *(bf8*)&Vs[(t2 * 16 + col) * 72 + 32 + quad * 8];
                acc[t2] = MFMA(a0, b0, acc[t2]);
                acc[t2] = MFMA(a1, b1, acc[t2]);
            }
            __syncthreads();
        }
#pragma unroll
        for (int t2 = 0; t2 < 4; ++t2) {
            if (t2 >= nf) break;
            int fglob = fg * 64 + t2 * 16 + col;
            int kc = fglob >> 5, fi = fglob & 31;
#pragma unroll
            for (int r = 0; r < 4; ++r) {
                int m = mt + w * 16 + quad * 4 + r;
                long adr = ((long)(b * 128 + (m >> 5))) * NSP + (m & 31) * 32
                         + (long)kc * 1024 + fi;
                catb[adr] = f2b(acc[t2][r] + b2f(kvb[adr]));
            }
        }
    } else {
        int x2 = x - 208;                        // 0..959
        int att = (x2 < 320) ? 1 : 2;
        int ft  = (att == 1) ? x2 : x2 - 320;    // att1: 0..319, att2: 0..639
        int KC  = (att == 1) ? 160 : 320;
        const u16* vt = (att == 1) ? vt1 : vt2;
        const u16* Prow = Pb12 + ((att == 1) ? 0 : 102400) + (long)b * 160 * 160;
        u16* Vs = lds;                           // 16 x 168 (f rows, p cols)
        for (int g = tid; g < 320; g += 256) {   // V stage (once): 16f x 160p
            int fl = g / 20, p8 = (g % 20) * 8;
            int fglob = ft * 16 + fl;
            int kc = fglob >> 5, fr = fglob & 31;
            *(bf8*)&Vs[fl * 168 + p8] =
                *(const bf8*)(vt + (((long)b * KC + kc) * 32 + fr) * 160 + p8);
        }
        __syncthreads();
        int fglob = ft * 16 + col;
        int kcf = fglob >> 5, fi = fglob & 31;
        long cbase = chunk_off(att, kcf) + fi;
        f4 z = {0.f, 0.f, 0.f, 0.f};
        for (int j = 0; j < 3; ++j) {            // wave streams mi = w, w+4, w+8
            int mi = w + 4 * j;
            if (mi >= 10) break;
            int nkk = (mi >> 1) + 1;             // triangular K depth (1..5)
            f4 acc = z;
#pragma unroll 5
            for (int kk = 0; kk < nkk; ++kk) {
                bf8 a  = *(const bf8*)(Prow + (mi * 16 + col) * 160 + kk * 32 + quad * 8);
                bf8 bb = *(bf8*)&Vs[col * 168 + kk * 32 + quad * 8];
                acc = MFMA(a, bb, acc);
            }
#pragma unroll
            for (int r = 0; r < 4; ++r) {
                int m = mi * 16 + quad * 4 + r;
                long adr = row_base(att, b, m) + cbase;
                catb[adr] = f2b(acc[r] + b2f(kvb[adr]));
            }
        }
    }
}

// ---------------- K6: FUSED tail: transpose + LN + MLP + out ----------------
__global__ __launch_bounds__(256) void k_mlp_fused(
        const u16* __restrict__ catb, const float* __restrict__ g,
        const float* __restrict__ be, const u16* __restrict__ wbt,
        const u16* __restrict__ w2o, float* __restrict__ out) {
    // grid (1600)
    int x = blockIdx.x, tid = threadIdx.x;
    int tt = x * 64;
    int bn = tt >> 10, hwt = tt & 1023;
    int b = bn / 25, uv = bn - b * 25;
    __shared__ u16 CT[64 * 136];      // raw ct -> ln'd ct -> h1
    __shared__ u16 Wt[128 * 136];     // Wo -> W1 -> W2o
    __shared__ float gl[128], bl[128], mu_s[64], rs_s[64];
    int w = tid >> 6, l = tid & 63, quad = l >> 4, col = l & 15;
    const u16* src = catb + (long)b * 128 * NSP + (long)uv * HWC + hwt;
#pragma unroll
    for (int i = 0; i < 4; ++i) {
        int gi = i * 256 + tid;
        int d = gi >> 3, hw8 = (gi & 7) * 8;
        bf8 v = *(const bf8*)(src + (long)d * NSP + hw8);
#pragma unroll
        for (int j = 0; j < 8; ++j) CT[(hw8 + j) * 136 + d] = ((u16*)&v)[j];
    }
    {   // stage Wo (64 x 128) into Wt rows 0..63
        const u16* Wob = wbt + 49152;
        for (int q = tid; q < 1024; q += 256) {
            int o = q >> 4, k8 = (q & 15) * 8;
            *(bf8*)&Wt[o * 136 + k8] = *(const bf8*)(Wob + o * 128 + k8);
        }
    }
    if (tid < 128) { gl[tid] = g[tid]; bl[tid] = be[tid]; }
    __syncthreads();
    f4 z = {0.f, 0.f, 0.f, 0.f};
    // GEMM_B: acc_o = ct @ Wo
    f4 acc_o[4]; for (int i = 0; i < 4; ++i) acc_o[i] = z;
#pragma unroll
    for (int kc = 0; kc < 4; ++kc) {
        bf8 a = *(bf8*)&CT[(w * 16 + col) * 136 + kc * 32 + quad * 8];
#pragma unroll
        for (int nt = 0; nt < 4; ++nt) {
            bf8 bb = *(bf8*)&Wt[(nt * 16 + col) * 136 + kc * 32 + quad * 8];
            acc_o[nt] = MFMA(a, bb, acc_o[nt]);
        }
    }
    {   // LN stats
        int tk = w * 16 + (l >> 2), dg = (l & 3) * 32;
        float s = 0.f, s2 = 0.f;
#pragma unroll
        for (int q = 0; q < 4; ++q) {
            bf8 vv = *(bf8*)&CT[tk * 136 + dg + q * 8];
#pragma unroll
            for (int j = 0; j < 8; ++j) { float f = b2f(((u16*)&vv)[j]); s += f; s2 += f * f; }
        }
        s += __shfl_xor(s, 1); s2 += __shfl_xor(s2, 1);
        s += __shfl_xor(s, 2); s2 += __shfl_xor(s2, 2);
        if ((l & 3) == 0) {
            float m = s * (1.f / 128.f);
            float var = s2 * (1.f / 128.f) - m * m;
            mu_s[tk] = m; rs_s[tk] = rsqrtf(var + 1e-5f);
        }
    }
    __syncthreads();
    // LN-transform CT in place; stage W1
    for (int q = tid; q < 1024; q += 256) {
        int row = q >> 4, k8 = (q & 15) * 8;
        bf8 cv = *(bf8*)&CT[row * 136 + k8];
        float m = mu_s[row], rs = rs_s[row];
        bf8 av;
#pragma unroll
        for (int j = 0; j < 8; ++j)
            ((u16*)&av)[j] = f2b((b2f(((u16*)&cv)[j]) - m) * rs * gl[k8 + j] + bl[k8 + j]);
        *(bf8*)&CT[row * 136 + k8] = av;
    }
    {
        const u16* W1b = wbt + 16384;
        for (int q = tid; q < 2048; q += 256) {
            int n = q >> 4, k8 = (q & 15) * 8;
            *(bf8*)&Wt[n * 136 + k8] = *(const bf8*)(W1b + n * 128 + k8);
        }
    }
    __syncthreads();
    // GEMM1: h1 = ln_ct @ W1
    f4 acc_h[8]; for (int i = 0; i < 8; ++i) acc_h[i] = z;
#pragma unroll
    for (int kc = 0; kc < 4; ++kc) {
        bf8 a = *(bf8*)&CT[(w * 16 + col) * 136 + kc * 32 + quad * 8];
#pragma unroll
        for (int nt = 0; nt < 8; ++nt) {
            bf8 bb = *(bf8*)&Wt[(nt * 16 + col) * 136 + kc * 32 + quad * 8];
            acc_h[nt] = MFMA(a, bb, acc_h[nt]);
        }
    }
    __syncthreads();
#pragma unroll
    for (int nt = 0; nt < 8; ++nt)
#pragma unroll
        for (int r = 0; r < 4; ++r) {
            int row = w * 16 + quad * 4 + r, n = nt * 16 + col;
            CT[row * 136 + n] = f2b(fmaxf(acc_h[nt][r], 0.f));
        }
    for (int q = tid; q < 1024; q += 256) {
        int o = q >> 4, k8 = (q & 15) * 8;
        *(bf8*)&Wt[o * 136 + k8] = *(const bf8*)(w2o + o * 128 + k8);
    }
    __syncthreads();
    // GEMM_A: acc_o += h1 @ W2o
#pragma unroll
    for (int kc = 0; kc < 4; ++kc) {
        bf8 a = *(bf8*)&CT[(w * 16 + col) * 136 + kc * 32 + quad * 8];
#pragma unroll
        for (int nt = 0; nt < 4; ++nt) {
            bf8 bb = *(bf8*)&Wt[(nt * 16 + col) * 136 + kc * 32 + quad * 8];
            acc_o[nt] = MFMA(a, bb, acc_o[nt]);
        }
    }
    int hw = hwt + w * 16 + quad * 4;
#pragma unroll
    for (int nt = 0; nt < 4; ++nt) {
        int o = nt * 16 + col;
        float4 pk = {acc_o[nt][0], acc_o[nt][1], acc_o[nt][2], acc_o[nt][3]};
        *(float4*)(out + ((long)((b * 64 + o) * 25 + uv)) * 1024 + hw) = pk;
    }
}

// ---------------- launch ---------------------------------------------------
extern "C" void kernel_launch(void* const* d_in, const int* in_sizes, int n_in,
                              void* d_out, int out_size, void* d_ws, size_t ws_size,
                              hipStream_t stream) {
    const float* x_lf = (const float*)d_in[0];
    const float* x_hf = (const float*)d_in[1];
    const float* W_in = (const float*)d_in[2];
    const float* W_kv = (const float*)d_in[3];
    const float* ln_g = (const float*)d_in[4];
    const float* ln_b = (const float*)d_in[5];
    const float* W_m1 = (const float*)d_in[6];
    const float* W_m2 = (const float*)d_in[7];
    const float* W_ot = (const float*)d_in[8];
    float* out = (float*)d_out;

    float* ws = (float*)d_ws;
    u16*   qb    = (u16*)ws;
    u16*   kvb   = (u16*)(ws + 6553600);
    u16*   catb  = (u16*)(ws + 13107200);
    u16*   Sb    = (u16*)(ws + 26214400);
    u16*   Pb    = (u16*)(ws + 28311552);
    u16*   Pb12  = (u16*)(ws + 30408704);
    float* Spart = ws + 30511104;                     // att1@0, att2@614400
    float* nq    = ws + 32354304;                     // att0@0,att1@4096,att2@4736
    float* nk    = ws + 32359680;
    u16*   w2ob  = (u16*)(ws + 32365056);
    u16*   vt0   = (u16*)(ws + 32569856);             // ends 34,208,256
    u16*   vt1   = (u16*)(ws + 34208256);             // ends 35,846,656
    u16*   vt2   = (u16*)(ws + 35846656);             // ends 39,123,456
    u16*   wbt   = (u16*)(ws + 39123456);             // after vt2

    // 0. one-time weight conversion + fused W2@Wo (one launch)
    k_prep<<<dim3(256), 256, 0, stream>>>(W_in, W_kv, W_m1, W_m2, W_ot, wbt, w2ob);

    // 1. token GEMMs -> bf16 q/kv
    k_tokens<<<dim3(400, 4, 2), 256, 0, stream>>>(x_hf, x_lf, wbt, qb, kvb);

    // 2. MERGED: S-GEMMs (64x64 BK=64) + V^T tiles (att1/2 batched) + norms
    k_sgemm_all<<<dim3(1938, 4), 256, 0, stream>>>(qb, kvb, vt0, vt1, vt2,
                                                   nq, nk, Sb, Spart);

    // 3. fused softmaxes (applies normalization via reciprocal norms)
    k_softmax_all<<<dim3(576, 4), 256, 0, stream>>>(Sb, Pb, Spart, nq, nk, Pb12);

    // 4. fused O-GEMMs + residual (att0 widened to 64f)
    k_ogemm_all<<<dim3(1168, 4), 256, 0, stream>>>(Pb, vt0, Pb12, vt1, vt2, kvb, catb);

    // 5. fused tail: transpose + LN + MLP + out
    k_mlp_fused<<<dim3(1600), 256, 0, stream>>>(catb, ln_g, ln_b, wbt, w2ob, out);
}

// Round 11
// 262.829 us; speedup vs baseline: 1.0134x; 1.0134x over previous
//
#include <hip/hip_runtime.h>

#define NSP   25600   // 25*32*32 spatial elems per (b, channel)
#define HWC   1024    // 32*32

typedef __attribute__((ext_vector_type(8))) short bf8;   // 8 bf16 = 4 VGPRs
typedef __attribute__((ext_vector_type(4))) float f4;    // MFMA C/D frag
#define MFMA(a,b,c) __builtin_amdgcn_mfma_f32_16x16x32_bf16(a, b, c, 0, 0, 0)
typedef unsigned short u16;

__device__ __forceinline__ u16 f2b(float f) {
    union { float f; unsigned u; } v; v.f = f;
    unsigned r = v.u + 0x7fffu + ((v.u >> 16) & 1u);
    return (u16)(r >> 16);
}
__device__ __forceinline__ float b2f(u16 h) {
    union { unsigned u; float f; } v; v.u = ((unsigned)h) << 16;
    return v.f;
}

// Attention addressing (K re-chunked into 32-contig-elem blocks; legal since
// fold K-order only needs consistency between q/k/v/unfold).
__device__ __forceinline__ long row_base(int att, int b, int m) {
    if (att == 0) { int cc = m >> 5, h = m & 31;   return ((long)(b*128 + cc))*NSP + h*32; }
    else if (att == 1) { int cc = m / 5, u = m - cc*5; return ((long)(b*128 + 32 + cc))*NSP + u*5120; }
    else { int h = m / 5, u = m - h*5;            return ((long)(b*128 + 64))*NSP + u*5120 + h*32; }
}
__device__ __forceinline__ long chunk_off(int att, int kc) {
    if (att == 0) return (long)kc * 1024;
    else if (att == 1) return (long)kc * 32;
    else { int cc = kc / 5, v = kc - cc*5; return (long)cc*NSP + v*1024; }
}

// ---------------- K0: one-time weight convert (+ fused W2@Wo) --------------
__global__ __launch_bounds__(256) void k_prep(
        const float* __restrict__ Wi, const float* __restrict__ Wk,
        const float* __restrict__ W1, const float* __restrict__ W2,
        const float* __restrict__ Wo, u16* __restrict__ wbt,
        u16* __restrict__ w2o) {
    int x = blockIdx.x, tid = threadIdx.x;
    if (x < 224) {
        int e = x * 256 + tid;                   // 57344 total
        const float* src; int base, K, N;
        if (e < 8192)       { src = Wi; base = 0;     K = 64;  N = 128; }
        else if (e < 16384) { src = Wk; base = 8192;  K = 64;  N = 128; }
        else if (e < 32768) { src = W1; base = 16384; K = 128; N = 128; }
        else if (e < 49152) { src = W2; base = 32768; K = 128; N = 128; }
        else                { src = Wo; base = 49152; K = 128; N = 64;  }
        int local = e - base, n = local / K, k = local - n * K;
        wbt[e] = f2b(src[k * N + n]);
    } else {
        int e = (x - 224) * 256 + tid;           // 8192 = 64 o x 128 k
        int o = e >> 7, k = e & 127;
        float s = 0.f;
        for (int n = 0; n < 128; ++n) s += W2[k * 128 + n] * Wo[n * 64 + o];
        w2o[e] = f2b(s);
    }
}

// ---------------- K1: token GEMMs (MFMA) -> bf16 q / kv --------------------
__global__ __launch_bounds__(256) void k_tokens(
        const float* __restrict__ x_hf, const float* __restrict__ x_lf,
        const u16* __restrict__ wbt,
        u16* __restrict__ qb, u16* __restrict__ kvb) {
    // grid (400, 4, 2)
    int s0 = blockIdx.x * 64, b = blockIdx.y, which = blockIdx.z;
    const float* x  = which ? x_lf : x_hf;
    const u16* Wb = wbt + (which ? 8192 : 0);    // [d][c] bf16
    u16* out = which ? kvb : qb;
    __shared__ u16 Axs[64 * 72];   // [token][c]
    __shared__ u16 Wl [128 * 72];  // [d][c]
    int tid = threadIdx.x;
    for (int g = tid; g < 1024; g += 256) {      // W stage: 16B contiguous
        int d = g >> 3, c8 = (g & 7) * 8;
        *(bf8*)&Wl[d * 72 + c8] = *(const bf8*)(Wb + d * 64 + c8);
    }
    for (int g = tid; g < 1024; g += 256) {      // x transpose, packed x4
        int s = g & 63, c4 = (g >> 6) * 4;
        long xb = ((long)(b * 64 + c4)) * NSP + s0 + s;
        ushort4 pk;
        pk.x = f2b(x[xb]);
        pk.y = f2b(x[xb + NSP]);
        pk.z = f2b(x[xb + 2 * NSP]);
        pk.w = f2b(x[xb + 3 * NSP]);
        *(ushort4*)&Axs[s * 72 + c4] = pk;
    }
    __syncthreads();
    int w = tid >> 6, l = tid & 63, quad = l >> 4, col = l & 15;
    f4 z = {0.f, 0.f, 0.f, 0.f};
    f4 acc[8]; for (int i = 0; i < 8; ++i) acc[i] = z;
#pragma unroll
    for (int kc = 0; kc < 2; ++kc) {
        bf8 a = *(bf8*)&Axs[(w * 16 + col) * 72 + kc * 32 + quad * 8];
#pragma unroll
        for (int nt = 0; nt < 8; ++nt) {
            bf8 bb = *(bf8*)&Wl[(nt * 16 + col) * 72 + kc * 32 + quad * 8];
            acc[nt] = MFMA(a, bb, acc[nt]);
        }
    }
#pragma unroll
    for (int nt = 0; nt < 8; ++nt) {
        int d = nt * 16 + col;
        long base = ((long)(b * 128 + d)) * NSP + s0 + w * 16 + quad * 4;
        ushort4 pk;
        pk.x = f2b(acc[nt][0]); pk.y = f2b(acc[nt][1]);
        pk.z = f2b(acc[nt][2]); pk.w = f2b(acc[nt][3]);
        *(ushort4*)(out + base) = pk;
    }
}

// ---------------- K3: MERGED S-GEMMs + V^T transposes + norms --------------
// att0 sgemm: 64x64 tiles, BK=64 (best measured: 53.2 us, R10).
// vt att1/2 batched 5x (block = 160p x 32f).
// Ranges: [0,136) att0; [136,586) split-K; [586,786) vt att0;
//         [786,946) vt att1; [946,1266) vt att2; [1266,1938) norms.
__global__ __launch_bounds__(256) void k_sgemm_all(
        const u16* __restrict__ qb, const u16* __restrict__ kvb,
        u16* __restrict__ vt0, u16* __restrict__ vt1, u16* __restrict__ vt2,
        float* __restrict__ nq, float* __restrict__ nk,
        u16* __restrict__ Sb, float* __restrict__ Spart) {
    __shared__ __align__(16) u16 lds[2 * 64 * 72];   // 18,432 B
    int x = blockIdx.x, b = blockIdx.y;
    int tid = threadIdx.x, w = tid >> 6, l = tid & 63, quad = l >> 4, col = l & 15;
    if (x < 136) {
        u16* Qs = lds;                // 64 x 72 (two 32-chunks per row)
        u16* Ks = lds + 64 * 72;
        int t = x, i = 0;
        while (t >= (i + 1) * (i + 2) / 2) ++i;
        int j = t - i * (i + 1) / 2;
        int mt = i * 64, nt = j * 64;
        int srow = tid >> 2, g = tid & 3;
        int mr = mt + srow, nr = nt + srow;
        long qrow = ((long)(b * 128 + (mr >> 5))) * NSP + (mr & 31) * 32;
        long krow = ((long)(b * 128 + (nr >> 5))) * NSP + (nr & 31) * 32;
        f4 z = {0.f, 0.f, 0.f, 0.f};
        f4 acc[4]; for (int q = 0; q < 4; ++q) acc[q] = z;
        for (int kc = 0; kc < 25; kc += 2) {     // BK=64 (2 chunks/stage)
            long co = (long)kc * 1024;
            bool two = (kc + 1 < 25);
            *(bf8*)&Qs[srow * 72 + g * 8] = *(const bf8*)(qb + qrow + co + g * 8);
            *(bf8*)&Ks[srow * 72 + g * 8] = *(const bf8*)(kvb + krow + co + g * 8);
            if (two) {
                *(bf8*)&Qs[srow * 72 + 32 + g * 8] =
                    *(const bf8*)(qb + qrow + co + 1024 + g * 8);
                *(bf8*)&Ks[srow * 72 + 32 + g * 8] =
                    *(const bf8*)(kvb + krow + co + 1024 + g * 8);
            }
            __syncthreads();
            bf8 a0 = *(bf8*)&Qs[(w * 16 + col) * 72 + quad * 8];
#pragma unroll
            for (int t2 = 0; t2 < 4; ++t2) {
                bf8 bb = *(bf8*)&Ks[(t2 * 16 + col) * 72 + quad * 8];
                acc[t2] = MFMA(a0, bb, acc[t2]);
            }
            if (two) {
                bf8 a1 = *(bf8*)&Qs[(w * 16 + col) * 72 + 32 + quad * 8];
#pragma unroll
                for (int t2 = 0; t2 < 4; ++t2) {
                    bf8 bb = *(bf8*)&Ks[(t2 * 16 + col) * 72 + 32 + quad * 8];
                    acc[t2] = MFMA(a1, bb, acc[t2]);
                }
            }
            __syncthreads();
        }
#pragma unroll
        for (int t2 = 0; t2 < 4; ++t2)
#pragma unroll
            for (int r = 0; r < 4; ++r) {
                int m = mt + w * 16 + quad * 4 + r, n = nt + t2 * 16 + col;
                float v = (n <= m) ? acc[t2][r] : 0.f;      // RAW (norm deferred)
                Sb[((long)b * 1024 + m) * 1024 + n] = f2b(v);
            }
    } else if (x < 586) {
        float* fl = (float*)lds;                 // 4096 floats = 16 KB
        int x2 = x - 136;                        // 0..449
        int t = x2 % 15, y = x2 / 15;            // y 0..29
        int att, split, nsplit; float* base;
        if (y < 10) { att = 1; split = y;      nsplit = 10; base = Spart; }
        else        { att = 2; split = y - 10; nsplit = 20; base = Spart + 614400; }
        int i = 0;
        while (t >= (i + 1) * (i + 2) / 2) ++i;
        int j = t - i * (i + 1) / 2;
        int mt = i * 32, nt = j * 32;
        long rm0 = row_base(att, b, mt + col),      rm1 = row_base(att, b, mt + 16 + col);
        long rn0 = row_base(att, b, nt + col),      rn1 = row_base(att, b, nt + 16 + col);
        int ko = quad * 8;
        f4 z = {0.f, 0.f, 0.f, 0.f};
        f4 a00 = z, a01 = z, a10 = z, a11 = z;
#pragma unroll
        for (int s = 0; s < 4; ++s) {
            int kc = split * 16 + w * 4 + s;
            long co = chunk_off(att, kc);
            bf8 qa0 = *(const bf8*)(qb + rm0 + co + ko);
            bf8 qa1 = *(const bf8*)(qb + rm1 + co + ko);
            bf8 kb0 = *(const bf8*)(kvb + rn0 + co + ko);
            bf8 kb1 = *(const bf8*)(kvb + rn1 + co + ko);
            a00 = MFMA(qa0, kb0, a00); a01 = MFMA(qa0, kb1, a01);
            a10 = MFMA(qa1, kb0, a10); a11 = MFMA(qa1, kb1, a11);
        }
        float* my = fl + w * 1024;
#pragma unroll
        for (int r = 0; r < 4; ++r) {
            my[(quad * 4 + r) * 32 + col]            = a00[r];
            my[(quad * 4 + r) * 32 + 16 + col]       = a01[r];
            my[(16 + quad * 4 + r) * 32 + col]       = a10[r];
            my[(16 + quad * 4 + r) * 32 + 16 + col]  = a11[r];
        }
        __syncthreads();
        float* dst = base + ((long)((b * 15 + t) * nsplit + split)) * 1024;
        for (int e = tid; e < 1024; e += 256)
            dst[e] = fl[e] + fl[1024 + e] + fl[2048 + e] + fl[3072 + e];
    } else if (x < 786) {                        // vt att0: 128 p x 32 f
        u16* T = lds;                            // 128 x 36
        int xv = x - 586;                        // 0..199
        int kc = xv >> 3, pt = (xv & 7) * 128;
        long co = (long)kc * 1024;
#pragma unroll
        for (int i = 0; i < 4; ++i) {
            int idx = i * 256 + tid;
            int r = idx >> 3, fq = (idx & 7) * 4;
            ushort4 e = *(const ushort4*)(kvb + row_base(0, b, pt + r) + co + fq);
            *(ushort4*)&T[r * 36 + fq] = e;
        }
        __syncthreads();
#pragma unroll
        for (int i = 0; i < 4; ++i) {
            int idx = i * 256 + tid;
            int f = idx >> 5, p4 = (idx & 31) * 4;
            ushort4 pk;
            pk.x = T[(p4    ) * 36 + f];
            pk.y = T[(p4 + 1) * 36 + f];
            pk.z = T[(p4 + 2) * 36 + f];
            pk.w = T[(p4 + 3) * 36 + f];
            *(ushort4*)(vt0 + (((long)b * 25 + kc) * 32 + f) * 1024 + pt + p4) = pk;
        }
    } else if (x < 1266) {                       // vt att1/2 BATCHED: 160p x 32f
        u16* T = lds;                            // 160 x 36 = 11.5 KB
        int att, kc, KC; u16* vt;
        if (x < 946) { att = 1; kc = x - 786; KC = 160; vt = vt1; }
        else         { att = 2; kc = x - 946; KC = 320; vt = vt2; }
        long co = chunk_off(att, kc);
        for (int g = tid; g < 1280; g += 256) {  // read 160 rows x 32 f
            int r = g >> 3, fq = (g & 7) * 4;
            ushort4 e = *(const ushort4*)(kvb + row_base(att, b, r) + co + fq);
            *(ushort4*)&T[r * 36 + fq] = e;
        }
        __syncthreads();
        for (int g = tid; g < 1280; g += 256) {  // write 32 f x 160 p
            int f = g / 40, p4 = (g % 40) * 4;
            ushort4 pk;
            pk.x = T[(p4    ) * 36 + f];
            pk.y = T[(p4 + 1) * 36 + f];
            pk.z = T[(p4 + 2) * 36 + f];
            pk.w = T[(p4 + 3) * 36 + f];
            *(ushort4*)(vt + (((long)b * KC + kc) * 32 + f) * 160 + p4) = pk;
        }
    } else {                                     // norms -> store RECIPROCAL
        int x2 = x - 1266;                       // 0..671
        int which = x2 >= 336;
        int g = which ? x2 - 336 : x2;           // 0..335
        int att, m0, KC;
        if (g < 256)      { att = 0; m0 = g * 4;         KC = 25;  }
        else if (g < 296) { att = 1; m0 = (g - 256) * 4; KC = 160; }
        else              { att = 2; m0 = (g - 296) * 4; KC = 320; }
        const u16* src = which ? kvb : qb;
        float* dst = which ? nk : nq;
        int ww = tid >> 6, lane = tid & 63;
        int m = m0 + ww;
        long base = row_base(att, b, m);
        int K = KC * 32;
        float s = 0.f;
        for (int k8 = lane * 8; k8 < K; k8 += 512) {
            bf8 v = *(const bf8*)(src + base + chunk_off(att, k8 >> 5) + (k8 & 31));
#pragma unroll
            for (int j = 0; j < 8; ++j) { float f = b2f(((u16*)&v)[j]); s += f * f; }
        }
        for (int o = 32; o >= 1; o >>= 1) s += __shfl_xor(s, o);
        if (lane == 0) {
            int off = (att == 0) ? b * 1024 + m
                                 : ((att == 1) ? 4096 : 4736) + b * 160 + m;
            dst[off] = 1.f / fmaxf(sqrtf(s), 1e-12f);
        }
    }
}

// ---------------- K4: fused softmaxes (applies normalization) --------------
__global__ __launch_bounds__(256) void k_softmax_all(
        const u16* __restrict__ Sb, u16* __restrict__ Pb,
        const float* __restrict__ Spart, const float* __restrict__ nq,
        const float* __restrict__ nk, u16* __restrict__ Pb12) {
    // grid (576, 4): x<256 -> att0 wave-per-row; else att1/2 column softmax
    int xb = blockIdx.x, b = blockIdx.y, tid = threadIdx.x;
    if (xb < 256) {
        int w = tid >> 6, lane = tid & 63;
        int m = xb * 4 + w;
        const u16* row = Sb + ((long)b * 1024 + m) * 1024;
        u16* pr = Pb + ((long)b * 1024 + m) * 1024;
        int e0 = lane * 16;
        float rq = nq[b * 1024 + m];             // reciprocal norms
        const float* nkb = nk + b * 1024 + e0;
        float rk[16];
        *(float4*)&rk[0]  = *(const float4*)(nkb);
        *(float4*)&rk[4]  = *(const float4*)(nkb + 4);
        *(float4*)&rk[8]  = *(const float4*)(nkb + 8);
        *(float4*)&rk[12] = *(const float4*)(nkb + 12);
        bf8 x0 = *(const bf8*)(row + e0);
        bf8 x1 = *(const bf8*)(row + e0 + 8);
        float v[16];
#pragma unroll
        for (int j = 0; j < 8; ++j) {
            v[j]     = b2f(((u16*)&x0)[j]) * rq * rk[j];
            v[8 + j] = b2f(((u16*)&x1)[j]) * rq * rk[8 + j];
        }
        float mx = -1e30f;
#pragma unroll
        for (int j = 0; j < 16; ++j) if (e0 + j <= m) mx = fmaxf(mx, v[j]);
#pragma unroll
        for (int o = 32; o >= 1; o >>= 1) mx = fmaxf(mx, __shfl_xor(mx, o));
        float s = 0.f;
#pragma unroll
        for (int j = 0; j < 16; ++j) {
            float e = (e0 + j <= m) ? __expf(v[j] - mx) : 0.f;
            v[j] = e; s += e;
        }
#pragma unroll
        for (int o = 32; o >= 1; o >>= 1) s += __shfl_xor(s, o);
        float inv = 1.f / s;
        bf8 o0, o1;
#pragma unroll
        for (int j = 0; j < 8; ++j) {
            ((u16*)&o0)[j] = f2b(v[j] * inv);
            ((u16*)&o1)[j] = f2b(v[8 + j] * inv);
        }
        *(bf8*)(pr + e0) = o0;
        *(bf8*)(pr + e0 + 8) = o1;
    } else {
        int x = xb - 256;                        // 0..319
        int att = (x < 160) ? 1 : 2;
        int m = (att == 1) ? x : x - 160;
        int nsplit = (att == 1) ? 10 : 20;
        const float* base = (att == 1) ? Spart : Spart + 614400;
        int noff = (att == 1) ? 4096 : 4736;
        u16* P = Pb12 + ((att == 1) ? 0 : 102400);
        int i = m >> 5, ro = (m & 31) * 32;
        int n = tid;
        bool act = (n <= m) && (n < 160);
        float myv = 0.f;
        if (act) {
            int t = i * (i + 1) / 2 + (n >> 5);
            const float* src = base + ((long)((b * 15 + t) * nsplit)) * 1024 + ro + (n & 31);
            float s = 0.f;
            for (int sp = 0; sp < nsplit; ++sp) s += src[(long)sp * 1024];
            myv = s * (nq[noff + b * 160 + m] * nk[noff + b * 160 + n]);  // reciprocals
        }
        __shared__ float red[256];
        red[tid] = act ? myv : -1e30f; __syncthreads();
        for (int w = 128; w >= 1; w >>= 1) {
            if (tid < w) red[tid] = fmaxf(red[tid], red[tid + w]);
            __syncthreads();
        }
        float mx = red[0]; __syncthreads();
        float e = act ? __expf(myv - mx) : 0.f;
        red[tid] = e; __syncthreads();
        for (int w = 128; w >= 1; w >>= 1) {
            if (tid < w) red[tid] += red[tid + w];
            __syncthreads();
        }
        float inv = 1.f / red[0];
        if (n < 160) P[((long)b * 160 + m) * 160 + n] = f2b(e * inv);
    }
}

// ---------------- K5: fused O-GEMMs + residual (R3/R9 proven 400-block) ----
__global__ __launch_bounds__(256) void k_ogemm_all(
        const u16* __restrict__ Pb, const u16* __restrict__ vt0,
        const u16* __restrict__ Pb12, const u16* __restrict__ vt1,
        const u16* __restrict__ vt2, const u16* __restrict__ kvb,
        u16* __restrict__ catb) {
    // grid (1360, 4): x<400 -> att0; 400..719 -> att1; 720..1359 -> att2
    __shared__ __align__(16) u16 lds[64 * 72 + 32 * 72];   // 13,824 B
    int x = blockIdx.x, b = blockIdx.y;
    int tid = threadIdx.x, w = tid >> 6, l = tid & 63, quad = l >> 4, col = l & 15;
    if (x < 400) {
        int mtt = x & 15, kc = x >> 4;
        int mt = mtt * 64;
        long co = (long)kc * 1024;
        const u16* vtc = vt0 + ((long)b * 25 + kc) * 32 * 1024;
        u16* Ps = lds;              // 64 x 72 (rows m-local, cols p-slab 64)
        u16* Vs = lds + 64 * 72;    // 32 x 72 (rows f-local, cols p-slab 64)
        f4 z = {0.f, 0.f, 0.f, 0.f};
        f4 acc[2]; acc[0] = z; acc[1] = z;
        for (int s = 0; s <= mtt; ++s) {         // p = 0 .. mt+64 (P zero past m)
            int p0 = s * 64;
#pragma unroll
            for (int i = 0; i < 2; ++i) {        // P stage: 64 x 64
                int idx = i * 256 + tid;
                int row = idx >> 3, c8 = (idx & 7) * 8;
                *(bf8*)&Ps[row * 72 + c8] =
                    *(const bf8*)(Pb + ((long)(b * 1024 + mt + row)) * 1024 + p0 + c8);
            }
            {                                    // V stage: 32 x 64
                int f = tid >> 3, p8 = (tid & 7) * 8;
                *(bf8*)&Vs[f * 72 + p8] =
                    *(const bf8*)(vtc + (long)f * 1024 + p0 + p8);
            }
            __syncthreads();
            bf8 a0 = *(bf8*)&Ps[(w * 16 + col) * 72 + quad * 8];
            bf8 a1 = *(bf8*)&Ps[(w * 16 + col) * 72 + 32 + quad * 8];
#pragma unroll
            for (int t2 = 0; t2 < 2; ++t2) {
                bf8 b0 = *(bf8*)&Vs[(t2 * 16 + col) * 72 + quad * 8];
                bf8 b1 = *(bf8*)&Vs[(t2 * 16 + col) * 72 + 32 + quad * 8];
                acc[t2] = MFMA(a0, b0, acc[t2]);
                acc[t2] = MFMA(a1, b1, acc[t2]);
            }
            __syncthreads();
        }
#pragma unroll
        for (int t2 = 0; t2 < 2; ++t2)
#pragma unroll
            for (int r = 0; r < 4; ++r) {
                int m = mt + w * 16 + quad * 4 + r, f = t2 * 16 + col;
                long adr = ((long)(b * 128 + (m >> 5))) * NSP + (m & 31) * 32 + co + f;
                catb[adr] = f2b(acc[t2][r] + b2f(kvb[adr]));
            }
    } else {
        int x2 = x - 400;                        // 0..959
        int att = (x2 < 320) ? 1 : 2;
        int ft  = (att == 1) ? x2 : x2 - 320;    // att1: 0..319, att2: 0..639
        int KC  = (att == 1) ? 160 : 320;
        const u16* vt = (att == 1) ? vt1 : vt2;
        const u16* Prow = Pb12 + ((att == 1) ? 0 : 102400) + (long)b * 160 * 160;
        u16* Vs = lds;                           // 16 x 168 (f rows, p cols)
        for (int g = tid; g < 320; g += 256) {   // V stage (once): 16f x 160p
            int fl = g / 20, p8 = (g % 20) * 8;
            int fglob = ft * 16 + fl;
            int kc = fglob >> 5, fr = fglob & 31;
            *(bf8*)&Vs[fl * 168 + p8] =
                *(const bf8*)(vt + (((long)b * KC + kc) * 32 + fr) * 160 + p8);
        }
        __syncthreads();
        int fglob = ft * 16 + col;
        int kcf = fglob >> 5, fi = fglob & 31;
        long cbase = chunk_off(att, kcf) + fi;
        f4 z = {0.f, 0.f, 0.f, 0.f};
        for (int j = 0; j < 3; ++j) {            // wave streams mi = w, w+4, w+8
            int mi = w + 4 * j;
            if (mi >= 10) break;
            int nkk = (mi >> 1) + 1;             // triangular K depth (1..5)
            f4 acc = z;
#pragma unroll 5
            for (int kk = 0; kk < nkk; ++kk) {
                bf8 a  = *(const bf8*)(Prow + (mi * 16 + col) * 160 + kk * 32 + quad * 8);
                bf8 bb = *(bf8*)&Vs[col * 168 + kk * 32 + quad * 8];
                acc = MFMA(a, bb, acc);
            }
#pragma unroll
            for (int r = 0; r < 4; ++r) {
                int m = mi * 16 + quad * 4 + r;
                long adr = row_base(att, b, m) + cbase;
                catb[adr] = f2b(acc[r] + b2f(kvb[adr]));
            }
        }
    }
}

// ---------------- K6: FUSED tail: transpose + LN + MLP + out ----------------
__global__ __launch_bounds__(256) void k_mlp_fused(
        const u16* __restrict__ catb, const float* __restrict__ g,
        const float* __restrict__ be, const u16* __restrict__ wbt,
        const u16* __restrict__ w2o, float* __restrict__ out) {
    // grid (1600)
    int x = blockIdx.x, tid = threadIdx.x;
    int tt = x * 64;
    int bn = tt >> 10, hwt = tt & 1023;
    int b = bn / 25, uv = bn - b * 25;
    __shared__ u16 CT[64 * 136];      // raw ct -> ln'd ct -> h1
    __shared__ u16 Wt[128 * 136];     // Wo -> W1 -> W2o
    __shared__ float gl[128], bl[128], mu_s[64], rs_s[64];
    int w = tid >> 6, l = tid & 63, quad = l >> 4, col = l & 15;
    const u16* src = catb + (long)b * 128 * NSP + (long)uv * HWC + hwt;
#pragma unroll
    for (int i = 0; i < 4; ++i) {
        int gi = i * 256 + tid;
        int d = gi >> 3, hw8 = (gi & 7) * 8;
        bf8 v = *(const bf8*)(src + (long)d * NSP + hw8);
#pragma unroll
        for (int j = 0; j < 8; ++j) CT[(hw8 + j) * 136 + d] = ((u16*)&v)[j];
    }
    {   // stage Wo (64 x 128) into Wt rows 0..63
        const u16* Wob = wbt + 49152;
        for (int q = tid; q < 1024; q += 256) {
            int o = q >> 4, k8 = (q & 15) * 8;
            *(bf8*)&Wt[o * 136 + k8] = *(const bf8*)(Wob + o * 128 + k8);
        }
    }
    if (tid < 128) { gl[tid] = g[tid]; bl[tid] = be[tid]; }
    __syncthreads();
    f4 z = {0.f, 0.f, 0.f, 0.f};
    // GEMM_B: acc_o = ct @ Wo
    f4 acc_o[4]; for (int i = 0; i < 4; ++i) acc_o[i] = z;
#pragma unroll
    for (int kc = 0; kc < 4; ++kc) {
        bf8 a = *(bf8*)&CT[(w * 16 + col) * 136 + kc * 32 + quad * 8];
#pragma unroll
        for (int nt = 0; nt < 4; ++nt) {
            bf8 bb = *(bf8*)&Wt[(nt * 16 + col) * 136 + kc * 32 + quad * 8];
            acc_o[nt] = MFMA(a, bb, acc_o[nt]);
        }
    }
    {   // LN stats
        int tk = w * 16 + (l >> 2), dg = (l & 3) * 32;
        float s = 0.f, s2 = 0.f;
#pragma unroll
        for (int q = 0; q < 4; ++q) {
            bf8 vv = *(bf8*)&CT[tk * 136 + dg + q * 8];
#pragma unroll
            for (int j = 0; j < 8; ++j) { float f = b2f(((u16*)&vv)[j]); s += f; s2 += f * f; }
        }
        s += __shfl_xor(s, 1); s2 += __shfl_xor(s2, 1);
        s += __shfl_xor(s, 2); s2 += __shfl_xor(s2, 2);
        if ((l & 3) == 0) {
            float m = s * (1.f / 128.f);
            float var = s2 * (1.f / 128.f) - m * m;
            mu_s[tk] = m; rs_s[tk] = rsqrtf(var + 1e-5f);
        }
    }
    __syncthreads();
    // LN-transform CT in place; stage W1
    for (int q = tid; q < 1024; q += 256) {
        int row = q >> 4, k8 = (q & 15) * 8;
        bf8 cv = *(bf8*)&CT[row * 136 + k8];
        float m = mu_s[row], rs = rs_s[row];
        bf8 av;
#pragma unroll
        for (int j = 0; j < 8; ++j)
            ((u16*)&av)[j] = f2b((b2f(((u16*)&cv)[j]) - m) * rs * gl[k8 + j] + bl[k8 + j]);
        *(bf8*)&CT[row * 136 + k8] = av;
    }
    {
        const u16* W1b = wbt + 16384;
        for (int q = tid; q < 2048; q += 256) {
            int n = q >> 4, k8 = (q & 15) * 8;
            *(bf8*)&Wt[n * 136 + k8] = *(const bf8*)(W1b + n * 128 + k8);
        }
    }
    __syncthreads();
    // GEMM1: h1 = ln_ct @ W1
    f4 acc_h[8]; for (int i = 0; i < 8; ++i) acc_h[i] = z;
#pragma unroll
    for (int kc = 0; kc < 4; ++kc) {
        bf8 a = *(bf8*)&CT[(w * 16 + col) * 136 + kc * 32 + quad * 8];
#pragma unroll
        for (int nt = 0; nt < 8; ++nt) {
            bf8 bb = *(bf8*)&Wt[(nt * 16 + col) * 136 + kc * 32 + quad * 8];
            acc_h[nt] = MFMA(a, bb, acc_h[nt]);
        }
    }
    __syncthreads();
#pragma unroll
    for (int nt = 0; nt < 8; ++nt)
#pragma unroll
        for (int r = 0; r < 4; ++r) {
            int row = w * 16 + quad * 4 + r, n = nt * 16 + col;
            CT[row * 136 + n] = f2b(fmaxf(acc_h[nt][r], 0.f));
        }
    for (int q = tid; q < 1024; q += 256) {
        int o = q >> 4, k8 = (q & 15) * 8;
        *(bf8*)&Wt[o * 136 + k8] = *(const bf8*)(w2o + o * 128 + k8);
    }
    __syncthreads();
    // GEMM_A: acc_o += h1 @ W2o
#pragma unroll
    for (int kc = 0; kc < 4; ++kc) {
        bf8 a = *(bf8*)&CT[(w * 16 + col) * 136 + kc * 32 + quad * 8];
#pragma unroll
        for (int nt = 0; nt < 4; ++nt) {
            bf8 bb = *(bf8*)&Wt[(nt * 16 + col) * 136 + kc * 32 + quad * 8];
            acc_o[nt] = MFMA(a, bb, acc_o[nt]);
        }
    }
    int hw = hwt + w * 16 + quad * 4;
#pragma unroll
    for (int nt = 0; nt < 4; ++nt) {
        int o = nt * 16 + col;
        float4 pk = {acc_o[nt][0], acc_o[nt][1], acc_o[nt][2], acc_o[nt][3]};
        *(float4*)(out + ((long)((b * 64 + o) * 25 + uv)) * 1024 + hw) = pk;
    }
}

// ---------------- launch ---------------------------------------------------
extern "C" void kernel_launch(void* const* d_in, const int* in_sizes, int n_in,
                              void* d_out, int out_size, void* d_ws, size_t ws_size,
                              hipStream_t stream) {
    const float* x_lf = (const float*)d_in[0];
    const float* x_hf = (const float*)d_in[1];
    const float* W_in = (const float*)d_in[2];
    const float* W_kv = (const float*)d_in[3];
    const float* ln_g = (const float*)d_in[4];
    const float* ln_b = (const float*)d_in[5];
    const float* W_m1 = (const float*)d_in[6];
    const float* W_m2 = (const float*)d_in[7];
    const float* W_ot = (const float*)d_in[8];
    float* out = (float*)d_out;

    float* ws = (float*)d_ws;
    u16*   qb    = (u16*)ws;
    u16*   kvb   = (u16*)(ws + 6553600);
    u16*   catb  = (u16*)(ws + 13107200);
    u16*   Sb    = (u16*)(ws + 26214400);
    u16*   Pb    = (u16*)(ws + 28311552);
    u16*   Pb12  = (u16*)(ws + 30408704);
    float* Spart = ws + 30511104;                     // att1@0, att2@614400
    float* nq    = ws + 32354304;                     // att0@0,att1@4096,att2@4736
    float* nk    = ws + 32359680;
    u16*   w2ob  = (u16*)(ws + 32365056);
    u16*   vt0   = (u16*)(ws + 32569856);             // ends 34,208,256
    u16*   vt1   = (u16*)(ws + 34208256);             // ends 35,846,656
    u16*   vt2   = (u16*)(ws + 35846656);             // ends 39,123,456
    u16*   wbt   = (u16*)(ws + 39123456);             // after vt2

    // 0. one-time weight conversion + fused W2@Wo (one launch)
    k_prep<<<dim3(256), 256, 0, stream>>>(W_in, W_kv, W_m1, W_m2, W_ot, wbt, w2ob);

    // 1. token GEMMs -> bf16 q/kv
    k_tokens<<<dim3(400, 4, 2), 256, 0, stream>>>(x_hf, x_lf, wbt, qb, kvb);

    // 2. MERGED: S-GEMMs (64x64 BK=64) + V^T tiles (att1/2 batched) + norms
    k_sgemm_all<<<dim3(1938, 4), 256, 0, stream>>>(qb, kvb, vt0, vt1, vt2,
                                                   nq, nk, Sb, Spart);

    // 3. fused softmaxes (applies normalization via reciprocal norms)
    k_softmax_all<<<dim3(576, 4), 256, 0, stream>>>(Sb, Pb, Spart, nq, nk, Pb12);

    // 4. fused O-GEMMs + residual (R3/R9 proven 400-block att0)
    k_ogemm_all<<<dim3(1360, 4), 256, 0, stream>>>(Pb, vt0, Pb12, vt1, vt2, kvb, catb);

    // 5. fused tail: transpose + LN + MLP + out
    k_mlp_fused<<<dim3(1600), 256, 0, stream>>>(catb, ln_g, ln_b, wbt, w2ob, out);
}

// Round 12
// 254.685 us; speedup vs baseline: 1.0458x; 1.0320x over previous
//
#include <hip/hip_runtime.h>

#define NSP   25600   // 25*32*32 spatial elems per (b, channel)
#define HWC   1024    // 32*32

typedef __attribute__((ext_vector_type(8))) short bf8;   // 8 bf16 = 4 VGPRs
typedef __attribute__((ext_vector_type(4))) float f4;    // MFMA C/D frag
#define MFMA(a,b,c) __builtin_amdgcn_mfma_f32_16x16x32_bf16(a, b, c, 0, 0, 0)
typedef unsigned short u16;

__device__ __forceinline__ u16 f2b(float f) {
    union { float f; unsigned u; } v; v.f = f;
    unsigned r = v.u + 0x7fffu + ((v.u >> 16) & 1u);
    return (u16)(r >> 16);
}
__device__ __forceinline__ float b2f(u16 h) {
    union { unsigned u; float f; } v; v.u = ((unsigned)h) << 16;
    return v.f;
}

// Attention addressing (K re-chunked into 32-contig-elem blocks; legal since
// fold K-order only needs consistency between q/k/v/unfold).
__device__ __forceinline__ long row_base(int att, int b, int m) {
    if (att == 0) { int cc = m >> 5, h = m & 31;   return ((long)(b*128 + cc))*NSP + h*32; }
    else if (att == 1) { int cc = m / 5, u = m - cc*5; return ((long)(b*128 + 32 + cc))*NSP + u*5120; }
    else { int h = m / 5, u = m - h*5;            return ((long)(b*128 + 64))*NSP + u*5120 + h*32; }
}
__device__ __forceinline__ long chunk_off(int att, int kc) {
    if (att == 0) return (long)kc * 1024;
    else if (att == 1) return (long)kc * 32;
    else { int cc = kc / 5, v = kc - cc*5; return (long)cc*NSP + v*1024; }
}

// ---------------- K0: one-time weight convert (+ fused W2@Wo) --------------
__global__ __launch_bounds__(256) void k_prep(
        const float* __restrict__ Wi, const float* __restrict__ Wk,
        const float* __restrict__ W1, const float* __restrict__ W2,
        const float* __restrict__ Wo, u16* __restrict__ wbt,
        u16* __restrict__ w2o) {
    int x = blockIdx.x, tid = threadIdx.x;
    if (x < 224) {
        int e = x * 256 + tid;                   // 57344 total
        const float* src; int base, K, N;
        if (e < 8192)       { src = Wi; base = 0;     K = 64;  N = 128; }
        else if (e < 16384) { src = Wk; base = 8192;  K = 64;  N = 128; }
        else if (e < 32768) { src = W1; base = 16384; K = 128; N = 128; }
        else if (e < 49152) { src = W2; base = 32768; K = 128; N = 128; }
        else                { src = Wo; base = 49152; K = 128; N = 64;  }
        int local = e - base, n = local / K, k = local - n * K;
        wbt[e] = f2b(src[k * N + n]);
    } else {
        int e = (x - 224) * 256 + tid;           // 8192 = 64 o x 128 k
        int o = e >> 7, k = e & 127;
        float s = 0.f;
        for (int n = 0; n < 128; ++n) s += W2[k * 128 + n] * Wo[n * 64 + o];
        w2o[e] = f2b(s);
    }
}

// ---------------- K1: token GEMMs (MFMA) -> bf16 q / kv --------------------
__global__ __launch_bounds__(256) void k_tokens(
        const float* __restrict__ x_hf, const float* __restrict__ x_lf,
        const u16* __restrict__ wbt,
        u16* __restrict__ qb, u16* __restrict__ kvb) {
    // grid (400, 4, 2)
    int s0 = blockIdx.x * 64, b = blockIdx.y, which = blockIdx.z;
    const float* x  = which ? x_lf : x_hf;
    const u16* Wb = wbt + (which ? 8192 : 0);    // [d][c] bf16
    u16* out = which ? kvb : qb;
    __shared__ u16 Axs[64 * 72];   // [token][c]
    __shared__ u16 Wl [128 * 72];  // [d][c]
    int tid = threadIdx.x;
    for (int g = tid; g < 1024; g += 256) {      // W stage: 16B contiguous
        int d = g >> 3, c8 = (g & 7) * 8;
        *(bf8*)&Wl[d * 72 + c8] = *(const bf8*)(Wb + d * 64 + c8);
    }
    for (int g = tid; g < 1024; g += 256) {      // x transpose, packed x4
        int s = g & 63, c4 = (g >> 6) * 4;
        long xb = ((long)(b * 64 + c4)) * NSP + s0 + s;
        ushort4 pk;
        pk.x = f2b(x[xb]);
        pk.y = f2b(x[xb + NSP]);
        pk.z = f2b(x[xb + 2 * NSP]);
        pk.w = f2b(x[xb + 3 * NSP]);
        *(ushort4*)&Axs[s * 72 + c4] = pk;
    }
    __syncthreads();
    int w = tid >> 6, l = tid & 63, quad = l >> 4, col = l & 15;
    f4 z = {0.f, 0.f, 0.f, 0.f};
    f4 acc[8]; for (int i = 0; i < 8; ++i) acc[i] = z;
#pragma unroll
    for (int kc = 0; kc < 2; ++kc) {
        bf8 a = *(bf8*)&Axs[(w * 16 + col) * 72 + kc * 32 + quad * 8];
#pragma unroll
        for (int nt = 0; nt < 8; ++nt) {
            bf8 bb = *(bf8*)&Wl[(nt * 16 + col) * 72 + kc * 32 + quad * 8];
            acc[nt] = MFMA(a, bb, acc[nt]);
        }
    }
#pragma unroll
    for (int nt = 0; nt < 8; ++nt) {
        int d = nt * 16 + col;
        long base = ((long)(b * 128 + d)) * NSP + s0 + w * 16 + quad * 4;
        ushort4 pk;
        pk.x = f2b(acc[nt][0]); pk.y = f2b(acc[nt][1]);
        pk.z = f2b(acc[nt][2]); pk.w = f2b(acc[nt][3]);
        *(ushort4*)(out + base) = pk;
    }
}

// ---------------- K3: MERGED S-GEMMs + V^T transposes + norms --------------
// att0 sgemm: 64x64 tiles, BK=64, XCD-CLUSTERED: t = (x%8)*17 + x/8 so the
// 17 tiles on one XCD are logically consecutive (shared Q/K panels stay in
// that XCD's private L2; footprint ~1.2 MB << 4 MB).
// Ranges: [0,136) att0; [136,586) split-K; [586,786) vt att0;
//         [786,946) vt att1; [946,1266) vt att2; [1266,1938) norms.
__global__ __launch_bounds__(256) void k_sgemm_all(
        const u16* __restrict__ qb, const u16* __restrict__ kvb,
        u16* __restrict__ vt0, u16* __restrict__ vt1, u16* __restrict__ vt2,
        float* __restrict__ nq, float* __restrict__ nk,
        u16* __restrict__ Sb, float* __restrict__ Spart) {
    __shared__ __align__(16) u16 lds[2 * 64 * 72];   // 18,432 B
    int x = blockIdx.x, b = blockIdx.y;
    int tid = threadIdx.x, w = tid >> 6, l = tid & 63, quad = l >> 4, col = l & 15;
    if (x < 136) {
        u16* Qs = lds;                // 64 x 72 (two 32-chunks per row)
        u16* Ks = lds + 64 * 72;
        int t = (x % 8) * 17 + (x / 8);          // XCD-clustered logical tile
        int i = 0;
        while (t >= (i + 1) * (i + 2) / 2) ++i;
        int j = t - i * (i + 1) / 2;
        int mt = i * 64, nt = j * 64;
        int srow = tid >> 2, g = tid & 3;
        int mr = mt + srow, nr = nt + srow;
        long qrow = ((long)(b * 128 + (mr >> 5))) * NSP + (mr & 31) * 32;
        long krow = ((long)(b * 128 + (nr >> 5))) * NSP + (nr & 31) * 32;
        f4 z = {0.f, 0.f, 0.f, 0.f};
        f4 acc[4]; for (int q = 0; q < 4; ++q) acc[q] = z;
        for (int kc = 0; kc < 25; kc += 2) {     // BK=64 (2 chunks/stage)
            long co = (long)kc * 1024;
            bool two = (kc + 1 < 25);
            *(bf8*)&Qs[srow * 72 + g * 8] = *(const bf8*)(qb + qrow + co + g * 8);
            *(bf8*)&Ks[srow * 72 + g * 8] = *(const bf8*)(kvb + krow + co + g * 8);
            if (two) {
                *(bf8*)&Qs[srow * 72 + 32 + g * 8] =
                    *(const bf8*)(qb + qrow + co + 1024 + g * 8);
                *(bf8*)&Ks[srow * 72 + 32 + g * 8] =
                    *(const bf8*)(kvb + krow + co + 1024 + g * 8);
            }
            __syncthreads();
            bf8 a0 = *(bf8*)&Qs[(w * 16 + col) * 72 + quad * 8];
#pragma unroll
            for (int t2 = 0; t2 < 4; ++t2) {
                bf8 bb = *(bf8*)&Ks[(t2 * 16 + col) * 72 + quad * 8];
                acc[t2] = MFMA(a0, bb, acc[t2]);
            }
            if (two) {
                bf8 a1 = *(bf8*)&Qs[(w * 16 + col) * 72 + 32 + quad * 8];
#pragma unroll
                for (int t2 = 0; t2 < 4; ++t2) {
                    bf8 bb = *(bf8*)&Ks[(t2 * 16 + col) * 72 + 32 + quad * 8];
                    acc[t2] = MFMA(a1, bb, acc[t2]);
                }
            }
            __syncthreads();
        }
#pragma unroll
        for (int t2 = 0; t2 < 4; ++t2)
#pragma unroll
            for (int r = 0; r < 4; ++r) {
                int m = mt + w * 16 + quad * 4 + r, n = nt + t2 * 16 + col;
                float v = (n <= m) ? acc[t2][r] : 0.f;      // RAW (norm deferred)
                Sb[((long)b * 1024 + m) * 1024 + n] = f2b(v);
            }
    } else if (x < 586) {
        float* fl = (float*)lds;                 // 4096 floats = 16 KB
        int x2 = x - 136;                        // 0..449
        int t = x2 % 15, y = x2 / 15;            // y 0..29
        int att, split, nsplit; float* base;
        if (y < 10) { att = 1; split = y;      nsplit = 10; base = Spart; }
        else        { att = 2; split = y - 10; nsplit = 20; base = Spart + 614400; }
        int i = 0;
        while (t >= (i + 1) * (i + 2) / 2) ++i;
        int j = t - i * (i + 1) / 2;
        int mt = i * 32, nt = j * 32;
        long rm0 = row_base(att, b, mt + col),      rm1 = row_base(att, b, mt + 16 + col);
        long rn0 = row_base(att, b, nt + col),      rn1 = row_base(att, b, nt + 16 + col);
        int ko = quad * 8;
        f4 z = {0.f, 0.f, 0.f, 0.f};
        f4 a00 = z, a01 = z, a10 = z, a11 = z;
#pragma unroll
        for (int s = 0; s < 4; ++s) {
            int kc = split * 16 + w * 4 + s;
            long co = chunk_off(att, kc);
            bf8 qa0 = *(const bf8*)(qb + rm0 + co + ko);
            bf8 qa1 = *(const bf8*)(qb + rm1 + co + ko);
            bf8 kb0 = *(const bf8*)(kvb + rn0 + co + ko);
            bf8 kb1 = *(const bf8*)(kvb + rn1 + co + ko);
            a00 = MFMA(qa0, kb0, a00); a01 = MFMA(qa0, kb1, a01);
            a10 = MFMA(qa1, kb0, a10); a11 = MFMA(qa1, kb1, a11);
        }
        float* my = fl + w * 1024;
#pragma unroll
        for (int r = 0; r < 4; ++r) {
            my[(quad * 4 + r) * 32 + col]            = a00[r];
            my[(quad * 4 + r) * 32 + 16 + col]       = a01[r];
            my[(16 + quad * 4 + r) * 32 + col]       = a10[r];
            my[(16 + quad * 4 + r) * 32 + 16 + col]  = a11[r];
        }
        __syncthreads();
        float* dst = base + ((long)((b * 15 + t) * nsplit + split)) * 1024;
        for (int e = tid; e < 1024; e += 256)
            dst[e] = fl[e] + fl[1024 + e] + fl[2048 + e] + fl[3072 + e];
    } else if (x < 786) {                        // vt att0: 128 p x 32 f
        u16* T = lds;                            // 128 x 36
        int xv = x - 586;                        // 0..199
        int kc = xv >> 3, pt = (xv & 7) * 128;
        long co = (long)kc * 1024;
#pragma unroll
        for (int i = 0; i < 4; ++i) {
            int idx = i * 256 + tid;
            int r = idx >> 3, fq = (idx & 7) * 4;
            ushort4 e = *(const ushort4*)(kvb + row_base(0, b, pt + r) + co + fq);
            *(ushort4*)&T[r * 36 + fq] = e;
        }
        __syncthreads();
#pragma unroll
        for (int i = 0; i < 4; ++i) {
            int idx = i * 256 + tid;
            int f = idx >> 5, p4 = (idx & 31) * 4;
            ushort4 pk;
            pk.x = T[(p4    ) * 36 + f];
            pk.y = T[(p4 + 1) * 36 + f];
            pk.z = T[(p4 + 2) * 36 + f];
            pk.w = T[(p4 + 3) * 36 + f];
            *(ushort4*)(vt0 + (((long)b * 25 + kc) * 32 + f) * 1024 + pt + p4) = pk;
        }
    } else if (x < 1266) {                       // vt att1/2 BATCHED: 160p x 32f
        u16* T = lds;                            // 160 x 36 = 11.5 KB
        int att, kc, KC; u16* vt;
        if (x < 946) { att = 1; kc = x - 786; KC = 160; vt = vt1; }
        else         { att = 2; kc = x - 946; KC = 320; vt = vt2; }
        long co = chunk_off(att, kc);
        for (int g = tid; g < 1280; g += 256) {  // read 160 rows x 32 f
            int r = g >> 3, fq = (g & 7) * 4;
            ushort4 e = *(const ushort4*)(kvb + row_base(att, b, r) + co + fq);
            *(ushort4*)&T[r * 36 + fq] = e;
        }
        __syncthreads();
        for (int g = tid; g < 1280; g += 256) {  // write 32 f x 160 p
            int f = g / 40, p4 = (g % 40) * 4;
            ushort4 pk;
            pk.x = T[(p4    ) * 36 + f];
            pk.y = T[(p4 + 1) * 36 + f];
            pk.z = T[(p4 + 2) * 36 + f];
            pk.w = T[(p4 + 3) * 36 + f];
            *(ushort4*)(vt + (((long)b * KC + kc) * 32 + f) * 160 + p4) = pk;
        }
    } else {                                     // norms -> store RECIPROCAL
        int x2 = x - 1266;                       // 0..671
        int which = x2 >= 336;
        int g = which ? x2 - 336 : x2;           // 0..335
        int att, m0, KC;
        if (g < 256)      { att = 0; m0 = g * 4;         KC = 25;  }
        else if (g < 296) { att = 1; m0 = (g - 256) * 4; KC = 160; }
        else              { att = 2; m0 = (g - 296) * 4; KC = 320; }
        const u16* src = which ? kvb : qb;
        float* dst = which ? nk : nq;
        int ww = tid >> 6, lane = tid & 63;
        int m = m0 + ww;
        long base = row_base(att, b, m);
        int K = KC * 32;
        float s = 0.f;
        for (int k8 = lane * 8; k8 < K; k8 += 512) {
            bf8 v = *(const bf8*)(src + base + chunk_off(att, k8 >> 5) + (k8 & 31));
#pragma unroll
            for (int j = 0; j < 8; ++j) { float f = b2f(((u16*)&v)[j]); s += f * f; }
        }
        for (int o = 32; o >= 1; o >>= 1) s += __shfl_xor(s, o);
        if (lane == 0) {
            int off = (att == 0) ? b * 1024 + m
                                 : ((att == 1) ? 4096 : 4736) + b * 160 + m;
            dst[off] = 1.f / fmaxf(sqrtf(s), 1e-12f);
        }
    }
}

// ---------------- K4: fused softmaxes (applies normalization) --------------
__global__ __launch_bounds__(256) void k_softmax_all(
        const u16* __restrict__ Sb, u16* __restrict__ Pb,
        const float* __restrict__ Spart, const float* __restrict__ nq,
        const float* __restrict__ nk, u16* __restrict__ Pb12) {
    // grid (576, 4): x<256 -> att0 wave-per-row; else att1/2 column softmax
    int xb = blockIdx.x, b = blockIdx.y, tid = threadIdx.x;
    if (xb < 256) {
        int w = tid >> 6, lane = tid & 63;
        int m = xb * 4 + w;
        const u16* row = Sb + ((long)b * 1024 + m) * 1024;
        u16* pr = Pb + ((long)b * 1024 + m) * 1024;
        int e0 = lane * 16;
        float rq = nq[b * 1024 + m];             // reciprocal norms
        const float* nkb = nk + b * 1024 + e0;
        float rk[16];
        *(float4*)&rk[0]  = *(const float4*)(nkb);
        *(float4*)&rk[4]  = *(const float4*)(nkb + 4);
        *(float4*)&rk[8]  = *(const float4*)(nkb + 8);
        *(float4*)&rk[12] = *(const float4*)(nkb + 12);
        bf8 x0 = *(const bf8*)(row + e0);
        bf8 x1 = *(const bf8*)(row + e0 + 8);
        float v[16];
#pragma unroll
        for (int j = 0; j < 8; ++j) {
            v[j]     = b2f(((u16*)&x0)[j]) * rq * rk[j];
            v[8 + j] = b2f(((u16*)&x1)[j]) * rq * rk[8 + j];
        }
        float mx = -1e30f;
#pragma unroll
        for (int j = 0; j < 16; ++j) if (e0 + j <= m) mx = fmaxf(mx, v[j]);
#pragma unroll
        for (int o = 32; o >= 1; o >>= 1) mx = fmaxf(mx, __shfl_xor(mx, o));
        float s = 0.f;
#pragma unroll
        for (int j = 0; j < 16; ++j) {
            float e = (e0 + j <= m) ? __expf(v[j] - mx) : 0.f;
            v[j] = e; s += e;
        }
#pragma unroll
        for (int o = 32; o >= 1; o >>= 1) s += __shfl_xor(s, o);
        float inv = 1.f / s;
        bf8 o0, o1;
#pragma unroll
        for (int j = 0; j < 8; ++j) {
            ((u16*)&o0)[j] = f2b(v[j] * inv);
            ((u16*)&o1)[j] = f2b(v[8 + j] * inv);
        }
        *(bf8*)(pr + e0) = o0;
        *(bf8*)(pr + e0 + 8) = o1;
    } else {
        int x = xb - 256;                        // 0..319
        int att = (x < 160) ? 1 : 2;
        int m = (att == 1) ? x : x - 160;
        int nsplit = (att == 1) ? 10 : 20;
        const float* base = (att == 1) ? Spart : Spart + 614400;
        int noff = (att == 1) ? 4096 : 4736;
        u16* P = Pb12 + ((att == 1) ? 0 : 102400);
        int i = m >> 5, ro = (m & 31) * 32;
        int n = tid;
        bool act = (n <= m) && (n < 160);
        float myv = 0.f;
        if (act) {
            int t = i * (i + 1) / 2 + (n >> 5);
            const float* src = base + ((long)((b * 15 + t) * nsplit)) * 1024 + ro + (n & 31);
            float s = 0.f;
            for (int sp = 0; sp < nsplit; ++sp) s += src[(long)sp * 1024];
            myv = s * (nq[noff + b * 160 + m] * nk[noff + b * 160 + n]);  // reciprocals
        }
        __shared__ float red[256];
        red[tid] = act ? myv : -1e30f; __syncthreads();
        for (int w = 128; w >= 1; w >>= 1) {
            if (tid < w) red[tid] = fmaxf(red[tid], red[tid + w]);
            __syncthreads();
        }
        float mx = red[0]; __syncthreads();
        float e = act ? __expf(myv - mx) : 0.f;
        red[tid] = e; __syncthreads();
        for (int w = 128; w >= 1; w >>= 1) {
            if (tid < w) red[tid] += red[tid + w];
            __syncthreads();
        }
        float inv = 1.f / red[0];
        if (n < 160) P[((long)b * 160 + m) * 160 + n] = f2b(e * inv);
    }
}

// ---------------- K5: fused O-GEMMs + residual (XCD-clustered att0) --------
// att0: 400 blocks (proven best), remapped so each XCD owns mtt pair
// {k, 15-k} (balanced: (k+1)+(16-k)=17) with all 25 kc-blocks sharing each
// P-panel on ONE XCD's L2 (panel <= 139 KB, fetched ~once per XCD).
__global__ __launch_bounds__(256) void k_ogemm_all(
        const u16* __restrict__ Pb, const u16* __restrict__ vt0,
        const u16* __restrict__ Pb12, const u16* __restrict__ vt1,
        const u16* __restrict__ vt2, const u16* __restrict__ kvb,
        u16* __restrict__ catb) {
    // grid (1360, 4): x<400 -> att0; 400..719 -> att1; 720..1359 -> att2
    __shared__ __align__(16) u16 lds[64 * 72 + 32 * 72];   // 13,824 B
    int x = blockIdx.x, b = blockIdx.y;
    int tid = threadIdx.x, w = tid >> 6, l = tid & 63, quad = l >> 4, col = l & 15;
    if (x < 400) {
        int k8 = x % 8, c = x / 8;               // XCD id, pos in chunk (0..49)
        int mtt = (c < 25) ? k8 : 15 - k8;       // balanced mtt pair per XCD
        int kc  = (c < 25) ? c : c - 25;
        int mt = mtt * 64;
        long co = (long)kc * 1024;
        const u16* vtc = vt0 + ((long)b * 25 + kc) * 32 * 1024;
        u16* Ps = lds;              // 64 x 72 (rows m-local, cols p-slab 64)
        u16* Vs = lds + 64 * 72;    // 32 x 72 (rows f-local, cols p-slab 64)
        f4 z = {0.f, 0.f, 0.f, 0.f};
        f4 acc[2]; acc[0] = z; acc[1] = z;
        for (int s = 0; s <= mtt; ++s) {         // p = 0 .. mt+64 (P zero past m)
            int p0 = s * 64;
#pragma unroll
            for (int i = 0; i < 2; ++i) {        // P stage: 64 x 64
                int idx = i * 256 + tid;
                int row = idx >> 3, c8 = (idx & 7) * 8;
                *(bf8*)&Ps[row * 72 + c8] =
                    *(const bf8*)(Pb + ((long)(b * 1024 + mt + row)) * 1024 + p0 + c8);
            }
            {                                    // V stage: 32 x 64
                int f = tid >> 3, p8 = (tid & 7) * 8;
                *(bf8*)&Vs[f * 72 + p8] =
                    *(const bf8*)(vtc + (long)f * 1024 + p0 + p8);
            }
            __syncthreads();
            bf8 a0 = *(bf8*)&Ps[(w * 16 + col) * 72 + quad * 8];
            bf8 a1 = *(bf8*)&Ps[(w * 16 + col) * 72 + 32 + quad * 8];
#pragma unroll
            for (int t2 = 0; t2 < 2; ++t2) {
                bf8 b0 = *(bf8*)&Vs[(t2 * 16 + col) * 72 + quad * 8];
                bf8 b1 = *(bf8*)&Vs[(t2 * 16 + col) * 72 + 32 + quad * 8];
                acc[t2] = MFMA(a0, b0, acc[t2]);
                acc[t2] = MFMA(a1, b1, acc[t2]);
            }
            __syncthreads();
        }
#pragma unroll
        for (int t2 = 0; t2 < 2; ++t2)
#pragma unroll
            for (int r = 0; r < 4; ++r) {
                int m = mt + w * 16 + quad * 4 + r, f = t2 * 16 + col;
                long adr = ((long)(b * 128 + (m >> 5))) * NSP + (m & 31) * 32 + co + f;
                catb[adr] = f2b(acc[t2][r] + b2f(kvb[adr]));
            }
    } else {
        int x2 = x - 400;                        // 0..959
        int att = (x2 < 320) ? 1 : 2;
        int ft  = (att == 1) ? x2 : x2 - 320;    // att1: 0..319, att2: 0..639
        int KC  = (att == 1) ? 160 : 320;
        const u16* vt = (att == 1) ? vt1 : vt2;
        const u16* Prow = Pb12 + ((att == 1) ? 0 : 102400) + (long)b * 160 * 160;
        u16* Vs = lds;                           // 16 x 168 (f rows, p cols)
        for (int g = tid; g < 320; g += 256) {   // V stage (once): 16f x 160p
            int fl = g / 20, p8 = (g % 20) * 8;
            int fglob = ft * 16 + fl;
            int kc = fglob >> 5, fr = fglob & 31;
            *(bf8*)&Vs[fl * 168 + p8] =
                *(const bf8*)(vt + (((long)b * KC + kc) * 32 + fr) * 160 + p8);
        }
        __syncthreads();
        int fglob = ft * 16 + col;
        int kcf = fglob >> 5, fi = fglob & 31;
        long cbase = chunk_off(att, kcf) + fi;
        f4 z = {0.f, 0.f, 0.f, 0.f};
        for (int j = 0; j < 3; ++j) {            // wave streams mi = w, w+4, w+8
            int mi = w + 4 * j;
            if (mi >= 10) break;
            int nkk = (mi >> 1) + 1;             // triangular K depth (1..5)
            f4 acc = z;
#pragma unroll 5
            for (int kk = 0; kk < nkk; ++kk) {
                bf8 a  = *(const bf8*)(Prow + (mi * 16 + col) * 160 + kk * 32 + quad * 8);
                bf8 bb = *(bf8*)&Vs[col * 168 + kk * 32 + quad * 8];
                acc = MFMA(a, bb, acc);
            }
#pragma unroll
            for (int r = 0; r < 4; ++r) {
                int m = mi * 16 + quad * 4 + r;
                long adr = row_base(att, b, m) + cbase;
                catb[adr] = f2b(acc[r] + b2f(kvb[adr]));
            }
        }
    }
}

// ---------------- K6: FUSED tail: transpose + LN + MLP + out ----------------
__global__ __launch_bounds__(256) void k_mlp_fused(
        const u16* __restrict__ catb, const float* __restrict__ g,
        const float* __restrict__ be, const u16* __restrict__ wbt,
        const u16* __restrict__ w2o, float* __restrict__ out) {
    // grid (1600)
    int x = blockIdx.x, tid = threadIdx.x;
    int tt = x * 64;
    int bn = tt >> 10, hwt = tt & 1023;
    int b = bn / 25, uv = bn - b * 25;
    __shared__ u16 CT[64 * 136];      // raw ct -> ln'd ct -> h1
    __shared__ u16 Wt[128 * 136];     // Wo -> W1 -> W2o
    __shared__ float gl[128], bl[128], mu_s[64], rs_s[64];
    int w = tid >> 6, l = tid & 63, quad = l >> 4, col = l & 15;
    const u16* src = catb + (long)b * 128 * NSP + (long)uv * HWC + hwt;
#pragma unroll
    for (int i = 0; i < 4; ++i) {
        int gi = i * 256 + tid;
        int d = gi >> 3, hw8 = (gi & 7) * 8;
        bf8 v = *(const bf8*)(src + (long)d * NSP + hw8);
#pragma unroll
        for (int j = 0; j < 8; ++j) CT[(hw8 + j) * 136 + d] = ((u16*)&v)[j];
    }
    {   // stage Wo (64 x 128) into Wt rows 0..63
        const u16* Wob = wbt + 49152;
        for (int q = tid; q < 1024; q += 256) {
            int o = q >> 4, k8 = (q & 15) * 8;
            *(bf8*)&Wt[o * 136 + k8] = *(const bf8*)(Wob + o * 128 + k8);
        }
    }
    if (tid < 128) { gl[tid] = g[tid]; bl[tid] = be[tid]; }
    __syncthreads();
    f4 z = {0.f, 0.f, 0.f, 0.f};
    // GEMM_B: acc_o = ct @ Wo
    f4 acc_o[4]; for (int i = 0; i < 4; ++i) acc_o[i] = z;
#pragma unroll
    for (int kc = 0; kc < 4; ++kc) {
        bf8 a = *(bf8*)&CT[(w * 16 + col) * 136 + kc * 32 + quad * 8];
#pragma unroll
        for (int nt = 0; nt < 4; ++nt) {
            bf8 bb = *(bf8*)&Wt[(nt * 16 + col) * 136 + kc * 32 + quad * 8];
            acc_o[nt] = MFMA(a, bb, acc_o[nt]);
        }
    }
    {   // LN stats
        int tk = w * 16 + (l >> 2), dg = (l & 3) * 32;
        float s = 0.f, s2 = 0.f;
#pragma unroll
        for (int q = 0; q < 4; ++q) {
            bf8 vv = *(bf8*)&CT[tk * 136 + dg + q * 8];
#pragma unroll
            for (int j = 0; j < 8; ++j) { float f = b2f(((u16*)&vv)[j]); s += f; s2 += f * f; }
        }
        s += __shfl_xor(s, 1); s2 += __shfl_xor(s2, 1);
        s += __shfl_xor(s, 2); s2 += __shfl_xor(s2, 2);
        if ((l & 3) == 0) {
            float m = s * (1.f / 128.f);
            float var = s2 * (1.f / 128.f) - m * m;
            mu_s[tk] = m; rs_s[tk] = rsqrtf(var + 1e-5f);
        }
    }
    __syncthreads();
    // LN-transform CT in place; stage W1
    for (int q = tid; q < 1024; q += 256) {
        int row = q >> 4, k8 = (q & 15) * 8;
        bf8 cv = *(bf8*)&CT[row * 136 + k8];
        float m = mu_s[row], rs = rs_s[row];
        bf8 av;
#pragma unroll
        for (int j = 0; j < 8; ++j)
            ((u16*)&av)[j] = f2b((b2f(((u16*)&cv)[j]) - m) * rs * gl[k8 + j] + bl[k8 + j]);
        *(bf8*)&CT[row * 136 + k8] = av;
    }
    {
        const u16* W1b = wbt + 16384;
        for (int q = tid; q < 2048; q += 256) {
            int n = q >> 4, k8 = (q & 15) * 8;
            *(bf8*)&Wt[n * 136 + k8] = *(const bf8*)(W1b + n * 128 + k8);
        }
    }
    __syncthreads();
    // GEMM1: h1 = ln_ct @ W1
    f4 acc_h[8]; for (int i = 0; i < 8; ++i) acc_h[i] = z;
#pragma unroll
    for (int kc = 0; kc < 4; ++kc) {
        bf8 a = *(bf8*)&CT[(w * 16 + col) * 136 + kc * 32 + quad * 8];
#pragma unroll
        for (int nt = 0; nt < 8; ++nt) {
            bf8 bb = *(bf8*)&Wt[(nt * 16 + col) * 136 + kc * 32 + quad * 8];
            acc_h[nt] = MFMA(a, bb, acc_h[nt]);
        }
    }
    __syncthreads();
#pragma unroll
    for (int nt = 0; nt < 8; ++nt)
#pragma unroll
        for (int r = 0; r < 4; ++r) {
            int row = w * 16 + quad * 4 + r, n = nt * 16 + col;
            CT[row * 136 + n] = f2b(fmaxf(acc_h[nt][r], 0.f));
        }
    for (int q = tid; q < 1024; q += 256) {
        int o = q >> 4, k8 = (q & 15) * 8;
        *(bf8*)&Wt[o * 136 + k8] = *(const bf8*)(w2o + o * 128 + k8);
    }
    __syncthreads();
    // GEMM_A: acc_o += h1 @ W2o
#pragma unroll
    for (int kc = 0; kc < 4; ++kc) {
        bf8 a = *(bf8*)&CT[(w * 16 + col) * 136 + kc * 32 + quad * 8];
#pragma unroll
        for (int nt = 0; nt < 4; ++nt) {
            bf8 bb = *(bf8*)&Wt[(nt * 16 + col) * 136 + kc * 32 + quad * 8];
            acc_o[nt] = MFMA(a, bb, acc_o[nt]);
        }
    }
    int hw = hwt + w * 16 + quad * 4;
#pragma unroll
    for (int nt = 0; nt < 4; ++nt) {
        int o = nt * 16 + col;
        float4 pk = {acc_o[nt][0], acc_o[nt][1], acc_o[nt][2], acc_o[nt][3]};
        *(float4*)(out + ((long)((b * 64 + o) * 25 + uv)) * 1024 + hw) = pk;
    }
}

// ---------------- launch ---------------------------------------------------
extern "C" void kernel_launch(void* const* d_in, const int* in_sizes, int n_in,
                              void* d_out, int out_size, void* d_ws, size_t ws_size,
                              hipStream_t stream) {
    const float* x_lf = (const float*)d_in[0];
    const float* x_hf = (const float*)d_in[1];
    const float* W_in = (const float*)d_in[2];
    const float* W_kv = (const float*)d_in[3];
    const float* ln_g = (const float*)d_in[4];
    const float* ln_b = (const float*)d_in[5];
    const float* W_m1 = (const float*)d_in[6];
    const float* W_m2 = (const float*)d_in[7];
    const float* W_ot = (const float*)d_in[8];
    float* out = (float*)d_out;

    float* ws = (float*)d_ws;
    u16*   qb    = (u16*)ws;
    u16*   kvb   = (u16*)(ws + 6553600);
    u16*   catb  = (u16*)(ws + 13107200);
    u16*   Sb    = (u16*)(ws + 26214400);
    u16*   Pb    = (u16*)(ws + 28311552);
    u16*   Pb12  = (u16*)(ws + 30408704);
    float* Spart = ws + 30511104;                     // att1@0, att2@614400
    float* nq    = ws + 32354304;                     // att0@0,att1@4096,att2@4736
    float* nk    = ws + 32359680;
    u16*   w2ob  = (u16*)(ws + 32365056);
    u16*   vt0   = (u16*)(ws + 32569856);             // ends 34,208,256
    u16*   vt1   = (u16*)(ws + 34208256);             // ends 35,846,656
    u16*   vt2   = (u16*)(ws + 35846656);             // ends 39,123,456
    u16*   wbt   = (u16*)(ws + 39123456);             // after vt2

    // 0. one-time weight conversion + fused W2@Wo (one launch)
    k_prep<<<dim3(256), 256, 0, stream>>>(W_in, W_kv, W_m1, W_m2, W_ot, wbt, w2ob);

    // 1. token GEMMs -> bf16 q/kv
    k_tokens<<<dim3(400, 4, 2), 256, 0, stream>>>(x_hf, x_lf, wbt, qb, kvb);

    // 2. MERGED: S-GEMMs (XCD-clustered) + V^T tiles + norms
    k_sgemm_all<<<dim3(1938, 4), 256, 0, stream>>>(qb, kvb, vt0, vt1, vt2,
                                                   nq, nk, Sb, Spart);

    // 3. fused softmaxes (applies normalization via reciprocal norms)
    k_softmax_all<<<dim3(576, 4), 256, 0, stream>>>(Sb, Pb, Spart, nq, nk, Pb12);

    // 4. fused O-GEMMs + residual (XCD-clustered att0)
    k_ogemm_all<<<dim3(1360, 4), 256, 0, stream>>>(Pb, vt0, Pb12, vt1, vt2, kvb, catb);

    // 5. fused tail: transpose + LN + MLP + out
    k_mlp_fused<<<dim3(1600), 256, 0, stream>>>(catb, ln_g, ln_b, wbt, w2ob, out);
}